// Round 11
// baseline (236.274 us; speedup 1.0000x reference)
//
#include <hip/hip_runtime.h>
#include <hip/hip_bf16.h>

#define NB 8
#define NS 2048
#define ND 1024
#define NH 64
#define NM (NB*NS)   // 16384 rows

typedef __attribute__((ext_vector_type(8))) short short8;
typedef __attribute__((ext_vector_type(4))) short short4v;
typedef __attribute__((ext_vector_type(4))) float f32x4;
typedef __attribute__((ext_vector_type(4))) float f4;

// q pre-scale: fold 1/sqrt(64) and log2(e) so attention uses exp2 directly.
#define QSCALE (0.125f * 1.44269504088896340736f)

__device__ __forceinline__ unsigned short f2bf(float f) {
    union { __hip_bfloat16 h; unsigned short u; } cv;
    cv.h = __float2bfloat16(f);   // HW RTNE convert
    return cv.u;
}

// ---------------------------------------------------------------------------
// Kernel 0: weights -> bf16. Rows 0..63 Wq (pre-scaled), 64..127 Wk,
// 128..191 Wv (row-major [row][k]); plus Wob (bf16 Wo) and biasb.
// ---------------------------------------------------------------------------
__global__ __launch_bounds__(256) void convw_kernel(
    const float* __restrict__ Wq, const float* __restrict__ bq,
    const float* __restrict__ Wk, const float* __restrict__ bk,
    const float* __restrict__ Wv, const float* __restrict__ bv,
    const float* __restrict__ Wo,
    unsigned short* __restrict__ Wb, unsigned short* __restrict__ Wob,
    float* __restrict__ biasb)
{
    const int row = blockIdx.x;   // 0..255
    const int t = threadIdx.x;    // 0..255
    if (row < 192) {
        const float* W = row < 64 ? Wq : (row < 128 ? Wk : Wv);
        const float sc = row < 64 ? QSCALE : 1.0f;
        f4 v = *(const f4*)&W[(size_t)(row & 63) * ND + t * 4];
        short4v o;
#pragma unroll
        for (int j = 0; j < 4; ++j) o[j] = (short)f2bf(v[j] * sc);
        *(short4v*)&Wb[(size_t)row * ND + t * 4] = o;
        if (row == 0 && t < 192) {
            const float* bsrc = t < 64 ? bq : (t < 128 ? bk : bv);
            biasb[t] = bsrc[t & 63] * (t < 64 ? QSCALE : 1.0f);
        }
    } else if (t < 16) {
        f4 v = *(const f4*)&Wo[(size_t)(row - 192) * 64 + t * 4];
        short4v o;
#pragma unroll
        for (int j = 0; j < 4; ++j) o[j] = (short)f2bf(v[j]);
        *(short4v*)&Wob[(size_t)(row - 192) * 64 + t * 4] = o;
    }
}

// ---------------------------------------------------------------------------
// Kernel 1: QKV projection (exact R7 structure). rep>1 repeats the whole
// body (same stores each rep, idempotent) so a probe dispatch exceeds the
// ~40us profiler floor and exposes steady-state counters.
// ---------------------------------------------------------------------------
__global__ __launch_bounds__(512, 2) void qkv_kernel(
    const float* __restrict__ x, const unsigned short* __restrict__ Wb,
    const float* __restrict__ biasb,
    unsigned short* __restrict__ q, unsigned short* __restrict__ k,
    unsigned short* __restrict__ vT, int rep)
{
    __shared__ unsigned short As[2][64 * 64];
    __shared__ unsigned short Bs[2][192 * 64];

    const int t = threadIdx.x;
    const int lane = t & 63, g = lane >> 4, li = lane & 15;
    const int w = t >> 6, rg = w >> 2, cg = w & 3;
    const int m0 = blockIdx.x * 64;
    const int arow = t >> 3, ach = t & 7;

    f4 xa[2][2]; short8 wr[2][3];

#define QKV_LOAD(KS, SL)                                                          \
    {                                                                             \
        const float* p_ = &x[(size_t)(m0 + arow) * ND + (KS) * 64 + ach * 8];     \
        xa[SL][0] = *(const f4*)p_; xa[SL][1] = *(const f4*)(p_ + 4);             \
        wr[SL][0] = *(const short8*)&Wb[(size_t)(t >> 3) * ND + (KS) * 64 + (t & 7) * 8];                  \
        wr[SL][1] = *(const short8*)&Wb[(size_t)((t + 512) >> 3) * ND + (KS) * 64 + ((t + 512) & 7) * 8];  \
        wr[SL][2] = *(const short8*)&Wb[(size_t)((t + 1024) >> 3) * ND + (KS) * 64 + ((t + 1024) & 7) * 8];\
    }

#define QKV_COMMIT(SL, BUF)                                                       \
    {                                                                             \
        short8 av_;                                                               \
        for (int j_ = 0; j_ < 4; ++j_) {                                          \
            av_[j_] = (short)f2bf(xa[SL][0][j_]);                                 \
            av_[j_ + 4] = (short)f2bf(xa[SL][1][j_]);                             \
        }                                                                         \
        *(short8*)&As[BUF][arow * 64 + ((ach ^ (arow & 7)) << 3)] = av_;          \
        int r0_ = t >> 3, c0_ = t & 7;                                            \
        *(short8*)&Bs[BUF][r0_ * 64 + ((c0_ ^ (r0_ & 7)) << 3)] = wr[SL][0];      \
        int r1_ = (t + 512) >> 3, c1_ = (t + 512) & 7;                            \
        *(short8*)&Bs[BUF][r1_ * 64 + ((c1_ ^ (r1_ & 7)) << 3)] = wr[SL][1];      \
        int r2_ = (t + 1024) >> 3, c2_ = (t + 1024) & 7;                          \
        *(short8*)&Bs[BUF][r2_ * 64 + ((c2_ ^ (r2_ & 7)) << 3)] = wr[SL][2];      \
    }

    for (int rp = 0; rp < rep; ++rp) {
        f32x4 acc[2][3];
#pragma unroll
        for (int a = 0; a < 2; ++a)
#pragma unroll
            for (int nf = 0; nf < 3; ++nf) acc[a][nf] = (f32x4)0.f;

        QKV_LOAD(0, 0);
        QKV_LOAD(1, 1);
        QKV_COMMIT(0, 0);
        __syncthreads();

#pragma unroll
        for (int ks = 0; ks < 16; ++ks) {
            const int cur = ks & 1;
            if (ks < 14) QKV_LOAD(ks + 2, cur);
#pragma unroll
            for (int h = 0; h < 2; ++h) {
                short8 af0 = *(const short8*)&As[cur][(rg * 32 + 0 + li) * 64 + (((g + 4 * h) ^ (li & 7)) << 3)];
                short8 af1 = *(const short8*)&As[cur][(rg * 32 + 16 + li) * 64 + (((g + 4 * h) ^ (li & 7)) << 3)];
#pragma unroll
                for (int nf = 0; nf < 3; ++nf) {
                    short8 bf = *(const short8*)&Bs[cur][(cg * 48 + nf * 16 + li) * 64 + (((g + 4 * h) ^ (li & 7)) << 3)];
                    acc[0][nf] = __builtin_amdgcn_mfma_f32_16x16x32_bf16(af0, bf, acc[0][nf], 0, 0, 0);
                    acc[1][nf] = __builtin_amdgcn_mfma_f32_16x16x32_bf16(af1, bf, acc[1][nf], 0, 0, 0);
                }
            }
            if (ks < 15) QKV_COMMIT((ks + 1) & 1, cur ^ 1);
            __syncthreads();
        }

        // epilogue: bias + store (q,k row-major; v transposed [b][h][s])
#pragma unroll
        for (int nf = 0; nf < 3; ++nf) {
            const int col = cg * 48 + nf * 16 + li;
            const float bias = biasb[col];
#pragma unroll
            for (int a = 0; a < 2; ++a) {
                const int row0 = m0 + rg * 32 + a * 16 + 4 * g;
                if (col < 64) {
#pragma unroll
                    for (int i = 0; i < 4; ++i)
                        q[(size_t)(row0 + i) * NH + col] = f2bf(acc[a][nf][i] + bias);
                } else if (col < 128) {
#pragma unroll
                    for (int i = 0; i < 4; ++i)
                        k[(size_t)(row0 + i) * NH + (col - 64)] = f2bf(acc[a][nf][i] + bias);
                } else {
                    short4v pk;
#pragma unroll
                    for (int i = 0; i < 4; ++i) pk[i] = (short)f2bf(acc[a][nf][i] + bias);
                    const int bb = row0 >> 11, s = row0 & 2047;
                    *(short4v*)&vT[(size_t)(bb * NH + (col - 128)) * NS + s] = pk;
                }
            }
        }
    }
}

// ---------------------------------------------------------------------------
// Kernel 2: split-KV causal attention (exact R7 structure + rep probe).
// ---------------------------------------------------------------------------
__global__ __launch_bounds__(256, 2) void attn_kernel(
    const unsigned short* __restrict__ q, const unsigned short* __restrict__ k,
    const unsigned short* __restrict__ vT,
    float* __restrict__ Opart, float* __restrict__ lpart,
    int ctLog, int MAXC, int rep)
{
    __shared__ unsigned short Ks[2][64 * 64];
    __shared__ unsigned short Vs[2][64 * 64];
    __shared__ unsigned short Ps[4][16 * 64];

    const int t = threadIdx.x;
    const int w = t >> 6, lane = t & 63, g = lane >> 4, li = lane & 15;
    const int b = blockIdx.x & 7;          // batch -> XCD pinning
    const int pid = blockIdx.x >> 3;
    const int CT = 1 << ctLog;

    int qt = 0, c = 0;
    {
        int acc = 0;
        for (int u = 31; u >= 0; --u) {    // largest-work-first
            int nch = (u + CT) >> ctLog;
            if (pid < acc + nch) { qt = u; c = pid - acc; break; }
            acc += nch;
        }
    }
    const int t0 = c * CT;
    const int rem = qt + 1 - t0;
    const int tcount = rem < CT ? rem : CT;

    const size_t qkbase = (size_t)b * NS * NH;
    const int qrow = qt * 64 + w * 16 + li;
    const short8 qa0 = *(const short8*)&q[qkbase + (size_t)qrow * NH + g * 8];
    const short8 qa1 = *(const short8*)&q[qkbase + (size_t)qrow * NH + 32 + g * 8];

    const int srow = t >> 3, sch = t & 7;

    for (int rp = 0; rp < rep; ++rp) {
        float l_i[4]; f32x4 oacc[4];
#pragma unroll
        for (int i = 0; i < 4; ++i) { l_i[i] = 0.f; oacc[i] = (f32x4)0.f; }

        short8 kreg0, kreg1, vreg0, vreg1;
        {
            const int kv0 = t0 * 64;
            kreg0 = *(const short8*)&k[qkbase + (size_t)(kv0 + srow) * NH + sch * 8];
            kreg1 = *(const short8*)&k[qkbase + (size_t)(kv0 + srow + 32) * NH + sch * 8];
            vreg0 = *(const short8*)&vT[(size_t)(b * NH + srow) * NS + kv0 + sch * 8];
            vreg1 = *(const short8*)&vT[(size_t)(b * NH + srow + 32) * NS + kv0 + sch * 8];
            *(short8*)&Ks[0][srow * 64 + ((sch ^ (srow & 7)) << 3)] = kreg0;
            *(short8*)&Ks[0][(srow + 32) * 64 + ((sch ^ (srow & 7)) << 3)] = kreg1;
            *(short8*)&Vs[0][srow * 64 + ((sch ^ (srow & 7)) << 3)] = vreg0;
            *(short8*)&Vs[0][(srow + 32) * 64 + ((sch ^ (srow & 7)) << 3)] = vreg1;
        }
        __syncthreads();

        for (int tt = 0; tt < tcount; ++tt) {
            const int cur = tt & 1;
            const int kv0 = (t0 + tt) * 64;
            if (tt + 1 < tcount) {   // issue next-tile loads early (T14)
                const int nv0 = kv0 + 64;
                kreg0 = *(const short8*)&k[qkbase + (size_t)(nv0 + srow) * NH + sch * 8];
                kreg1 = *(const short8*)&k[qkbase + (size_t)(nv0 + srow + 32) * NH + sch * 8];
                vreg0 = *(const short8*)&vT[(size_t)(b * NH + srow) * NS + nv0 + sch * 8];
                vreg1 = *(const short8*)&vT[(size_t)(b * NH + srow + 32) * NS + nv0 + sch * 8];
            }
            // ---- QK^T: 16 q x 64 kv ----
            f32x4 s[4];
#pragma unroll
            for (int c4 = 0; c4 < 4; ++c4) {
                s[c4] = (f32x4)0.f;
                const int krow = 16 * c4 + li;
                short8 kf0 = *(const short8*)&Ks[cur][krow * 64 + ((g ^ (li & 7)) << 3)];
                s[c4] = __builtin_amdgcn_mfma_f32_16x16x32_bf16(qa0, kf0, s[c4], 0, 0, 0);
                short8 kf1 = *(const short8*)&Ks[cur][krow * 64 + (((g + 4) ^ (li & 7)) << 3)];
                s[c4] = __builtin_amdgcn_mfma_f32_16x16x32_bf16(qa1, kf1, s[c4], 0, 0, 0);
            }
            // ---- causal mask: only the diagonal tile ----
            if (kv0 == qt * 64) {
#pragma unroll
                for (int c4 = 0; c4 < 4; ++c4)
#pragma unroll
                    for (int i = 0; i < 4; ++i)
                        if (16 * c4 + li > w * 16 + 4 * g + i) s[c4][i] = -1e30f;
            }
            // ---- no-max softmax ----
            float p[4][4];
#pragma unroll
            for (int c4 = 0; c4 < 4; ++c4)
#pragma unroll
                for (int i = 0; i < 4; ++i)
                    p[c4][i] = exp2f(fminf(s[c4][i], 80.f));
#pragma unroll
            for (int i = 0; i < 4; ++i)
                l_i[i] += (p[0][i] + p[1][i]) + (p[2][i] + p[3][i]);

            // ---- P -> per-wave LDS (swizzled), then PV ----
#pragma unroll
            for (int c4 = 0; c4 < 4; ++c4)
#pragma unroll
                for (int i = 0; i < 4; ++i) {
                    const int prow = 4 * g + i;
                    const int chunk = 2 * c4 + (li >> 3);
                    Ps[w][prow * 64 + ((chunk ^ (prow & 7)) << 3) + (li & 7)] = f2bf(p[c4][i]);
                }
            short8 pf0 = *(const short8*)&Ps[w][li * 64 + ((g ^ (li & 7)) << 3)];
            short8 pf1 = *(const short8*)&Ps[w][li * 64 + (((g + 4) ^ (li & 7)) << 3)];
#pragma unroll
            for (int nf = 0; nf < 4; ++nf) {
                const int vrow = nf * 16 + li;
                short8 vf0 = *(const short8*)&Vs[cur][vrow * 64 + ((g ^ (li & 7)) << 3)];
                short8 vf1 = *(const short8*)&Vs[cur][vrow * 64 + (((g + 4) ^ (li & 7)) << 3)];
                oacc[nf] = __builtin_amdgcn_mfma_f32_16x16x32_bf16(pf0, vf0, oacc[nf], 0, 0, 0);
                oacc[nf] = __builtin_amdgcn_mfma_f32_16x16x32_bf16(pf1, vf1, oacc[nf], 0, 0, 0);
            }
            if (tt + 1 < tcount) {   // commit next tile late
                *(short8*)&Ks[cur ^ 1][srow * 64 + ((sch ^ (srow & 7)) << 3)] = kreg0;
                *(short8*)&Ks[cur ^ 1][(srow + 32) * 64 + ((sch ^ (srow & 7)) << 3)] = kreg1;
                *(short8*)&Vs[cur ^ 1][srow * 64 + ((sch ^ (srow & 7)) << 3)] = vreg0;
                *(short8*)&Vs[cur ^ 1][(srow + 32) * 64 + ((sch ^ (srow & 7)) << 3)] = vreg1;
            }
            __syncthreads();
        }

        // ---- one cross-lane l reduction per block ----
#pragma unroll
        for (int off = 1; off < 16; off <<= 1)
#pragma unroll
            for (int i = 0; i < 4; ++i) l_i[i] += __shfl_xor(l_i[i], off);

        const size_t slot = (size_t)((b * 32 + qt) * MAXC + c);
        float* Op = Opart + slot * 4096;
#pragma unroll
        for (int nf = 0; nf < 4; ++nf)
#pragma unroll
            for (int i = 0; i < 4; ++i)
                Op[(w * 16 + 4 * g + i) * 64 + nf * 16 + li] = oacc[nf][i];
        if (li == 0) {
#pragma unroll
            for (int i = 0; i < 4; ++i)
                lpart[slot * 64 + w * 16 + 4 * g + i] = l_i[i];
        }
        __syncthreads();   // LDS reuse across reps
    }
}

// ---------------------------------------------------------------------------
// Kernel 3: combine partials + MFMA output projection (+ rep probe)
// ---------------------------------------------------------------------------
__global__ __launch_bounds__(256, 2) void combine_kernel(
    const float* __restrict__ Opart, const float* __restrict__ lpart,
    const unsigned short* __restrict__ Wob, const float* __restrict__ bo,
    float* __restrict__ out, int ctLog, int MAXC, int rep)
{
    __shared__ unsigned short Osm[64 * 64];
    __shared__ float Linv[64];

    const int t = threadIdx.x;
    const int b = blockIdx.x & 7, qt = blockIdx.x >> 3;   // XCD-pinned to attn
    const int CT = 1 << ctLog;
    const int nch = (qt + CT) >> ctLog;
    const size_t base_slot = (size_t)(b * 32 + qt) * MAXC;

    for (int rp = 0; rp < rep; ++rp) {
        __syncthreads();   // LDS reuse across reps (no-op cost on rep 0)

        if (t < 64) {
            float L = 0.f;
            for (int cc = 0; cc < nch; ++cc)
                L += lpart[(base_slot + cc) * 64 + t];
            Linv[t] = 1.f / L;
        }

        const int r = t >> 2, c0 = (t & 3) * 16;
        f4 a0 = (f4)0.f, a1 = (f4)0.f, a2 = (f4)0.f, a3 = (f4)0.f;
        for (int cc = 0; cc < nch; ++cc) {
            const float* P = Opart + (base_slot + cc) * 4096 + r * 64 + c0;
            a0 += *(const f4*)P; a1 += *(const f4*)(P + 4);
            a2 += *(const f4*)(P + 8); a3 += *(const f4*)(P + 12);
        }
        __syncthreads();
        {
            const float sc = Linv[r];
            short8 o0, o1;
#pragma unroll
            for (int j = 0; j < 4; ++j) {
                o0[j] = (short)f2bf(a0[j] * sc); o0[j + 4] = (short)f2bf(a1[j] * sc);
                o1[j] = (short)f2bf(a2[j] * sc); o1[j + 4] = (short)f2bf(a3[j] * sc);
            }
            const int ch0 = (t & 3) * 2;
            *(short8*)&Osm[r * 64 + ((ch0 ^ (r & 7)) << 3)] = o0;
            *(short8*)&Osm[r * 64 + (((ch0 + 1) ^ (r & 7)) << 3)] = o1;
        }
        __syncthreads();

        const int w = t >> 6, lane = t & 63, g = lane >> 4, li = lane & 15;
        f32x4 acc[4];
#pragma unroll
        for (int nf = 0; nf < 4; ++nf) acc[nf] = (f32x4)0.f;
#pragma unroll
        for (int s = 0; s < 2; ++s) {
            const int rr = w * 16 + li;
            short8 af = *(const short8*)&Osm[rr * 64 + (((g + 4 * s) ^ (rr & 7)) << 3)];
#pragma unroll
            for (int nf = 0; nf < 4; ++nf) {
                short8 bf = *(const short8*)&Wob[(size_t)(nf * 16 + li) * 64 + s * 32 + g * 8];
                acc[nf] = __builtin_amdgcn_mfma_f32_16x16x32_bf16(af, bf, acc[nf], 0, 0, 0);
            }
        }
#pragma unroll
        for (int nf = 0; nf < 4; ++nf) {
            const float bias = bo[nf * 16 + li];
#pragma unroll
            for (int i = 0; i < 4; ++i) {
                const size_t row = (size_t)b * NS + qt * 64 + w * 16 + 4 * g + i;
                out[row * 64 + nf * 16 + li] = acc[nf][i] + bias;
            }
        }
    }
}

// ---------------------------------------------------------------------------
extern "C" void kernel_launch(void* const* d_in, const int* in_sizes, int n_in,
                              void* d_out, int out_size, void* d_ws, size_t ws_size,
                              hipStream_t stream)
{
    const float* x  = (const float*)d_in[0];
    const float* Wq = (const float*)d_in[1];
    const float* bq = (const float*)d_in[2];
    const float* Wk = (const float*)d_in[3];
    const float* bk = (const float*)d_in[4];
    const float* Wv = (const float*)d_in[5];
    const float* bv = (const float*)d_in[6];
    const float* Wo = (const float*)d_in[7];
    const float* bo = (const float*)d_in[8];
    float* out = (float*)d_out;

    size_t off = 0;
    auto alloc = [&](size_t bytes) {
        char* p = (char*)d_ws + off;
        off += (bytes + 255) & ~(size_t)255;
        return (void*)p;
    };
    unsigned short* qb  = (unsigned short*)alloc((size_t)NM * NH * 2);
    unsigned short* kb  = (unsigned short*)alloc((size_t)NM * NH * 2);
    unsigned short* vtb = (unsigned short*)alloc((size_t)NM * NH * 2);
    unsigned short* Wb  = (unsigned short*)alloc((size_t)192 * ND * 2);
    unsigned short* Wob = (unsigned short*)alloc((size_t)64 * 64 * 2);
    float* biasb = (float*)alloc(192 * 4);
    const size_t base = off;

    // KV-chunk size: prefer CT=8 (640 blocks), fall back if ws is tight.
    int ctLog = 5, MAXC = 1;
    const int cands[3] = {3, 4, 5};
    for (int ci = 0; ci < 3; ++ci) {
        const int cl = cands[ci];
        const int mc = (31 >> cl) + 1;
        const size_t nslot = (size_t)256 * mc;
        const size_t need = base + nslot * (4096 + 64) * 4 + 8192;
        if (need <= ws_size) { ctLog = cl; MAXC = mc; break; }
    }
    const size_t NSLOT = (size_t)256 * MAXC;
    float* Opart = (float*)alloc(NSLOT * 4096 * 4);
    float* lpart = (float*)alloc(NSLOT * 64 * 4);

    const int CT = 1 << ctLog;
    int NCperB = 0;
    for (int qt = 0; qt < 32; ++qt) NCperB += (qt + CT) >> ctLog;

    // ---- real pipeline (exact R7 configuration) ----
    convw_kernel<<<256, 256, 0, stream>>>(Wq, bq, Wk, bk, Wv, bv, Wo, Wb, Wob, biasb);
    qkv_kernel<<<NM / 64, 512, 0, stream>>>(x, Wb, biasb, qb, kb, vtb, 1);
    attn_kernel<<<8 * NCperB, 256, 0, stream>>>(qb, kb, vtb, Opart, lpart, ctLog, MAXC, 1);
    combine_kernel<<<256, 256, 0, stream>>>(Opart, lpart, Wob, bo, out, ctLog, MAXC, 1);

    // ---- PROBES: single dispatches long enough (>40us) to crack the
    // profiler's top-5. All idempotent (rewrite identical values). ----
    qkv_kernel<<<NM / 64, 512, 0, stream>>>(x, Wb, biasb, qb, kb, vtb, 4);
    attn_kernel<<<8 * NCperB, 256, 0, stream>>>(qb, kb, vtb, Opart, lpart, ctLog, MAXC, 3);
    combine_kernel<<<256, 256, 0, stream>>>(Opart, lpart, Wob, bo, out, ctLog, MAXC, 12);
}

// Round 12
// 57.065 us; speedup vs baseline: 4.1404x; 4.1404x over previous
//
#include <hip/hip_runtime.h>
#include <hip/hip_bf16.h>

#define NB 8
#define NS 2048
#define ND 1024
#define NH 64
#define NM (NB*NS)   // 16384 rows

typedef __attribute__((ext_vector_type(8))) short short8;
typedef __attribute__((ext_vector_type(4))) short short4v;
typedef __attribute__((ext_vector_type(4))) float f32x4;
typedef __attribute__((ext_vector_type(4))) float f4;

// q pre-scale: fold 1/sqrt(64) and log2(e) so attention uses exp2 directly.
#define QSCALE (0.125f * 1.44269504088896340736f)

__device__ __forceinline__ unsigned short f2bf(float f) {
    union { __hip_bfloat16 h; unsigned short u; } cv;
    cv.h = __float2bfloat16(f);   // HW RTNE convert
    return cv.u;
}

// ---------------------------------------------------------------------------
// Kernel 0: weights -> bf16. Rows 0..63 Wq (pre-scaled), 64..127 Wk,
// 128..191 Wv (row-major [row][k]); plus Wob (bf16 Wo) and biasb.
// ---------------------------------------------------------------------------
__global__ __launch_bounds__(256) void convw_kernel(
    const float* __restrict__ Wq, const float* __restrict__ bq,
    const float* __restrict__ Wk, const float* __restrict__ bk,
    const float* __restrict__ Wv, const float* __restrict__ bv,
    const float* __restrict__ Wo,
    unsigned short* __restrict__ Wb, unsigned short* __restrict__ Wob,
    float* __restrict__ biasb)
{
    const int row = blockIdx.x;   // 0..255
    const int t = threadIdx.x;    // 0..255
    if (row < 192) {
        const float* W = row < 64 ? Wq : (row < 128 ? Wk : Wv);
        const float sc = row < 64 ? QSCALE : 1.0f;
        f4 v = *(const f4*)&W[(size_t)(row & 63) * ND + t * 4];
        short4v o;
#pragma unroll
        for (int j = 0; j < 4; ++j) o[j] = (short)f2bf(v[j] * sc);
        *(short4v*)&Wb[(size_t)row * ND + t * 4] = o;
        if (row == 0 && t < 192) {
            const float* bsrc = t < 64 ? bq : (t < 128 ? bk : bv);
            biasb[t] = bsrc[t & 63] * (t < 64 ? QSCALE : 1.0f);
        }
    } else if (t < 16) {
        f4 v = *(const f4*)&Wo[(size_t)(row - 192) * 64 + t * 4];
        short4v o;
#pragma unroll
        for (int j = 0; j < 4; ++j) o[j] = (short)f2bf(v[j]);
        *(short4v*)&Wob[(size_t)(row - 192) * 64 + t * 4] = o;
    }
}

// ---------------------------------------------------------------------------
// Kernel 1: QKV projection, N-split for 2 blocks/CU co-residency (the R8/R11
// measured lever). Block = 64 rows x 96 cols, grid 512, LDS 40 KB, 8 waves.
// Wave = 16 rows x 48 cols. 2-deep register prefetch, LDS dbuf, XOR swizzle.
// Row-group's two halves are adjacent blockIdx (x second-touch is L3-hit).
// ---------------------------------------------------------------------------
__global__ __launch_bounds__(512, 4) void qkv_kernel(
    const float* __restrict__ x, const unsigned short* __restrict__ Wb,
    const float* __restrict__ biasb,
    unsigned short* __restrict__ q, unsigned short* __restrict__ k,
    unsigned short* __restrict__ vT)
{
    __shared__ unsigned short As[2][64 * 64];   // 16 KB
    __shared__ unsigned short Bs[2][96 * 64];   // 24 KB

    const int t = threadIdx.x;
    const int lane = t & 63, g = lane >> 4, li = lane & 15;
    const int w = t >> 6;
    const int rgw = w >> 1, cgw = w & 1;        // wave: 16 rows x 48 cols
    const int half = blockIdx.x & 1;            // which 96-col half
    const int m0 = (blockIdx.x >> 1) * 64;
    const int arow = t >> 3, ach = t & 7;
    const int wrow0 = t >> 3;                   // W chunk A: rows 0..63
    const int wrow1 = 64 + (t >> 3);            // W chunk B: rows 64..95 (t<256)
    const int wch = t & 7;
    const bool hasB = (t < 256);

    f32x4 acc[3];
#pragma unroll
    for (int nf = 0; nf < 3; ++nf) acc[nf] = (f32x4)0.f;

    f4 xa[2][2]; short8 wr[2][2];

#define QKV_LOAD(KS, SL)                                                          \
    {                                                                             \
        const float* p_ = &x[(size_t)(m0 + arow) * ND + (KS) * 64 + ach * 8];     \
        xa[SL][0] = *(const f4*)p_; xa[SL][1] = *(const f4*)(p_ + 4);             \
        wr[SL][0] = *(const short8*)&Wb[(size_t)(half * 96 + wrow0) * ND + (KS) * 64 + wch * 8]; \
        if (hasB)                                                                 \
            wr[SL][1] = *(const short8*)&Wb[(size_t)(half * 96 + wrow1) * ND + (KS) * 64 + wch * 8]; \
    }

#define QKV_COMMIT(SL, BUF)                                                       \
    {                                                                             \
        short8 av_;                                                               \
        for (int j_ = 0; j_ < 4; ++j_) {                                          \
            av_[j_] = (short)f2bf(xa[SL][0][j_]);                                 \
            av_[j_ + 4] = (short)f2bf(xa[SL][1][j_]);                             \
        }                                                                         \
        *(short8*)&As[BUF][arow * 64 + ((ach ^ (arow & 7)) << 3)] = av_;          \
        *(short8*)&Bs[BUF][wrow0 * 64 + ((wch ^ (wrow0 & 7)) << 3)] = wr[SL][0];  \
        if (hasB)                                                                 \
            *(short8*)&Bs[BUF][wrow1 * 64 + ((wch ^ (wrow1 & 7)) << 3)] = wr[SL][1]; \
    }

    QKV_LOAD(0, 0);
    QKV_LOAD(1, 1);
    QKV_COMMIT(0, 0);
    __syncthreads();

#pragma unroll
    for (int ks = 0; ks < 16; ++ks) {
        const int cur = ks & 1;
        if (ks < 14) QKV_LOAD(ks + 2, cur);
#pragma unroll
        for (int h = 0; h < 2; ++h) {
            short8 af = *(const short8*)&As[cur][(rgw * 16 + li) * 64 + (((g + 4 * h) ^ (li & 7)) << 3)];
#pragma unroll
            for (int nf = 0; nf < 3; ++nf) {
                short8 bf = *(const short8*)&Bs[cur][(cgw * 48 + nf * 16 + li) * 64 + (((g + 4 * h) ^ (li & 7)) << 3)];
                acc[nf] = __builtin_amdgcn_mfma_f32_16x16x32_bf16(af, bf, acc[nf], 0, 0, 0);
            }
        }
        if (ks < 15) QKV_COMMIT((ks + 1) & 1, cur ^ 1);
        __syncthreads();
    }

    // epilogue: bias + store (q,k row-major; v transposed [b][h][s])
#pragma unroll
    for (int nf = 0; nf < 3; ++nf) {
        const int col = half * 96 + cgw * 48 + nf * 16 + li;
        const float bias = biasb[col];
        const int row0 = m0 + rgw * 16 + 4 * g;
        if (col < 64) {
#pragma unroll
            for (int i = 0; i < 4; ++i)
                q[(size_t)(row0 + i) * NH + col] = f2bf(acc[nf][i] + bias);
        } else if (col < 128) {
#pragma unroll
            for (int i = 0; i < 4; ++i)
                k[(size_t)(row0 + i) * NH + (col - 64)] = f2bf(acc[nf][i] + bias);
        } else {
            short4v pk;
#pragma unroll
            for (int i = 0; i < 4; ++i) pk[i] = (short)f2bf(acc[nf][i] + bias);
            const int bb = row0 >> 11, s = row0 & 2047;
            *(short4v*)&vT[(size_t)(bb * NH + (col - 128)) * NS + s] = pk;
        }
    }
}

// ---------------------------------------------------------------------------
// Kernel 2: split-KV causal attention (R7, unchanged).
// ---------------------------------------------------------------------------
__global__ __launch_bounds__(256, 2) void attn_kernel(
    const unsigned short* __restrict__ q, const unsigned short* __restrict__ k,
    const unsigned short* __restrict__ vT,
    float* __restrict__ Opart, float* __restrict__ lpart,
    int ctLog, int MAXC)
{
    __shared__ unsigned short Ks[2][64 * 64];
    __shared__ unsigned short Vs[2][64 * 64];
    __shared__ unsigned short Ps[4][16 * 64];

    const int t = threadIdx.x;
    const int w = t >> 6, lane = t & 63, g = lane >> 4, li = lane & 15;
    const int b = blockIdx.x & 7;          // batch -> XCD pinning
    const int pid = blockIdx.x >> 3;
    const int CT = 1 << ctLog;

    int qt = 0, c = 0;
    {
        int acc = 0;
        for (int u = 31; u >= 0; --u) {    // largest-work-first
            int nch = (u + CT) >> ctLog;
            if (pid < acc + nch) { qt = u; c = pid - acc; break; }
            acc += nch;
        }
    }
    const int t0 = c * CT;
    const int rem = qt + 1 - t0;
    const int tcount = rem < CT ? rem : CT;

    const size_t qkbase = (size_t)b * NS * NH;
    const int qrow = qt * 64 + w * 16 + li;
    const short8 qa0 = *(const short8*)&q[qkbase + (size_t)qrow * NH + g * 8];
    const short8 qa1 = *(const short8*)&q[qkbase + (size_t)qrow * NH + 32 + g * 8];

    float l_i[4]; f32x4 oacc[4];
#pragma unroll
    for (int i = 0; i < 4; ++i) { l_i[i] = 0.f; oacc[i] = (f32x4)0.f; }

    const int srow = t >> 3, sch = t & 7;
    short8 kreg0, kreg1, vreg0, vreg1;

    {
        const int kv0 = t0 * 64;
        kreg0 = *(const short8*)&k[qkbase + (size_t)(kv0 + srow) * NH + sch * 8];
        kreg1 = *(const short8*)&k[qkbase + (size_t)(kv0 + srow + 32) * NH + sch * 8];
        vreg0 = *(const short8*)&vT[(size_t)(b * NH + srow) * NS + kv0 + sch * 8];
        vreg1 = *(const short8*)&vT[(size_t)(b * NH + srow + 32) * NS + kv0 + sch * 8];
        *(short8*)&Ks[0][srow * 64 + ((sch ^ (srow & 7)) << 3)] = kreg0;
        *(short8*)&Ks[0][(srow + 32) * 64 + ((sch ^ (srow & 7)) << 3)] = kreg1;
        *(short8*)&Vs[0][srow * 64 + ((sch ^ (srow & 7)) << 3)] = vreg0;
        *(short8*)&Vs[0][(srow + 32) * 64 + ((sch ^ (srow & 7)) << 3)] = vreg1;
    }
    __syncthreads();

    for (int tt = 0; tt < tcount; ++tt) {
        const int cur = tt & 1;
        const int kv0 = (t0 + tt) * 64;
        if (tt + 1 < tcount) {   // issue next-tile loads early (T14)
            const int nv0 = kv0 + 64;
            kreg0 = *(const short8*)&k[qkbase + (size_t)(nv0 + srow) * NH + sch * 8];
            kreg1 = *(const short8*)&k[qkbase + (size_t)(nv0 + srow + 32) * NH + sch * 8];
            vreg0 = *(const short8*)&vT[(size_t)(b * NH + srow) * NS + nv0 + sch * 8];
            vreg1 = *(const short8*)&vT[(size_t)(b * NH + srow + 32) * NS + nv0 + sch * 8];
        }
        // ---- QK^T: 16 q x 64 kv (scores already in log2 domain) ----
        f32x4 s[4];
#pragma unroll
        for (int c4 = 0; c4 < 4; ++c4) {
            s[c4] = (f32x4)0.f;
            const int krow = 16 * c4 + li;
            short8 kf0 = *(const short8*)&Ks[cur][krow * 64 + ((g ^ (li & 7)) << 3)];
            s[c4] = __builtin_amdgcn_mfma_f32_16x16x32_bf16(qa0, kf0, s[c4], 0, 0, 0);
            short8 kf1 = *(const short8*)&Ks[cur][krow * 64 + (((g + 4) ^ (li & 7)) << 3)];
            s[c4] = __builtin_amdgcn_mfma_f32_16x16x32_bf16(qa1, kf1, s[c4], 0, 0, 0);
        }
        // ---- causal mask: only the diagonal tile ----
        if (kv0 == qt * 64) {
#pragma unroll
            for (int c4 = 0; c4 < 4; ++c4)
#pragma unroll
                for (int i = 0; i < 4; ++i)
                    if (16 * c4 + li > w * 16 + 4 * g + i) s[c4][i] = -1e30f;
        }
        // ---- no-max softmax: p = exp2(min(s,80)), defer row-sum reduce ----
        float p[4][4];
#pragma unroll
        for (int c4 = 0; c4 < 4; ++c4)
#pragma unroll
            for (int i = 0; i < 4; ++i)
                p[c4][i] = exp2f(fminf(s[c4][i], 80.f));
#pragma unroll
        for (int i = 0; i < 4; ++i)
            l_i[i] += (p[0][i] + p[1][i]) + (p[2][i] + p[3][i]);

        // ---- P -> per-wave LDS (swizzled), then PV ----
#pragma unroll
        for (int c4 = 0; c4 < 4; ++c4)
#pragma unroll
            for (int i = 0; i < 4; ++i) {
                const int prow = 4 * g + i;
                const int chunk = 2 * c4 + (li >> 3);
                Ps[w][prow * 64 + ((chunk ^ (prow & 7)) << 3) + (li & 7)] = f2bf(p[c4][i]);
            }
        short8 pf0 = *(const short8*)&Ps[w][li * 64 + ((g ^ (li & 7)) << 3)];
        short8 pf1 = *(const short8*)&Ps[w][li * 64 + (((g + 4) ^ (li & 7)) << 3)];
#pragma unroll
        for (int nf = 0; nf < 4; ++nf) {
            const int vrow = nf * 16 + li;
            short8 vf0 = *(const short8*)&Vs[cur][vrow * 64 + ((g ^ (li & 7)) << 3)];
            short8 vf1 = *(const short8*)&Vs[cur][vrow * 64 + (((g + 4) ^ (li & 7)) << 3)];
            oacc[nf] = __builtin_amdgcn_mfma_f32_16x16x32_bf16(pf0, vf0, oacc[nf], 0, 0, 0);
            oacc[nf] = __builtin_amdgcn_mfma_f32_16x16x32_bf16(pf1, vf1, oacc[nf], 0, 0, 0);
        }
        if (tt + 1 < tcount) {   // commit next tile late
            *(short8*)&Ks[cur ^ 1][srow * 64 + ((sch ^ (srow & 7)) << 3)] = kreg0;
            *(short8*)&Ks[cur ^ 1][(srow + 32) * 64 + ((sch ^ (srow & 7)) << 3)] = kreg1;
            *(short8*)&Vs[cur ^ 1][srow * 64 + ((sch ^ (srow & 7)) << 3)] = vreg0;
            *(short8*)&Vs[cur ^ 1][(srow + 32) * 64 + ((sch ^ (srow & 7)) << 3)] = vreg1;
        }
        __syncthreads();
    }

    // ---- one cross-lane l reduction per block ----
#pragma unroll
    for (int off = 1; off < 16; off <<= 1)
#pragma unroll
        for (int i = 0; i < 4; ++i) l_i[i] += __shfl_xor(l_i[i], off);

    const size_t slot = (size_t)((b * 32 + qt) * MAXC + c);
    float* Op = Opart + slot * 4096;
#pragma unroll
    for (int nf = 0; nf < 4; ++nf)
#pragma unroll
        for (int i = 0; i < 4; ++i)
            Op[(w * 16 + 4 * g + i) * 64 + nf * 16 + li] = oacc[nf][i];
    if (li == 0) {
#pragma unroll
        for (int i = 0; i < 4; ++i)
            lpart[slot * 64 + w * 16 + 4 * g + i] = l_i[i];
    }
}

// ---------------------------------------------------------------------------
// Kernel 3: combine partials + MFMA output projection (out = O @ Wo^T + bo)
// ---------------------------------------------------------------------------
__global__ __launch_bounds__(256, 2) void combine_kernel(
    const float* __restrict__ Opart, const float* __restrict__ lpart,
    const unsigned short* __restrict__ Wob, const float* __restrict__ bo,
    float* __restrict__ out, int ctLog, int MAXC)
{
    __shared__ unsigned short Osm[64 * 64];
    __shared__ float Linv[64];

    const int t = threadIdx.x;
    const int b = blockIdx.x & 7, qt = blockIdx.x >> 3;   // XCD-pinned to attn
    const int CT = 1 << ctLog;
    const int nch = (qt + CT) >> ctLog;
    const size_t base_slot = (size_t)(b * 32 + qt) * MAXC;

    if (t < 64) {
        float L = 0.f;
        for (int cc = 0; cc < nch; ++cc)
            L += lpart[(base_slot + cc) * 64 + t];
        Linv[t] = 1.f / L;
    }

    // accumulate O' across chunks: thread owns row r, 16 cols
    const int r = t >> 2, c0 = (t & 3) * 16;
    f4 a0 = (f4)0.f, a1 = (f4)0.f, a2 = (f4)0.f, a3 = (f4)0.f;
    for (int cc = 0; cc < nch; ++cc) {
        const float* P = Opart + (base_slot + cc) * 4096 + r * 64 + c0;
        a0 += *(const f4*)P; a1 += *(const f4*)(P + 4);
        a2 += *(const f4*)(P + 8); a3 += *(const f4*)(P + 12);
    }
    __syncthreads();
    {
        const float sc = Linv[r];
        short8 o0, o1;
#pragma unroll
        for (int j = 0; j < 4; ++j) {
            o0[j] = (short)f2bf(a0[j] * sc); o0[j + 4] = (short)f2bf(a1[j] * sc);
            o1[j] = (short)f2bf(a2[j] * sc); o1[j + 4] = (short)f2bf(a3[j] * sc);
        }
        const int ch0 = (t & 3) * 2;
        *(short8*)&Osm[r * 64 + ((ch0 ^ (r & 7)) << 3)] = o0;
        *(short8*)&Osm[r * 64 + (((ch0 + 1) ^ (r & 7)) << 3)] = o1;
    }
    __syncthreads();

    // oproj: 4 waves x 16 rows, MFMA, B = Wo rows (bf16, L2)
    const int w = t >> 6, lane = t & 63, g = lane >> 4, li = lane & 15;
    f32x4 acc[4];
#pragma unroll
    for (int nf = 0; nf < 4; ++nf) acc[nf] = (f32x4)0.f;
#pragma unroll
    for (int s = 0; s < 2; ++s) {
        const int rr = w * 16 + li;
        short8 af = *(const short8*)&Osm[rr * 64 + (((g + 4 * s) ^ (rr & 7)) << 3)];
#pragma unroll
        for (int nf = 0; nf < 4; ++nf) {
            short8 bf = *(const short8*)&Wob[(size_t)(nf * 16 + li) * 64 + s * 32 + g * 8];
            acc[nf] = __builtin_amdgcn_mfma_f32_16x16x32_bf16(af, bf, acc[nf], 0, 0, 0);
        }
    }
#pragma unroll
    for (int nf = 0; nf < 4; ++nf) {
        const float bias = bo[nf * 16 + li];
#pragma unroll
        for (int i = 0; i < 4; ++i) {
            const size_t row = (size_t)b * NS + qt * 64 + w * 16 + 4 * g + i;
            out[row * 64 + nf * 16 + li] = acc[nf][i] + bias;
        }
    }
}

// ---------------------------------------------------------------------------
extern "C" void kernel_launch(void* const* d_in, const int* in_sizes, int n_in,
                              void* d_out, int out_size, void* d_ws, size_t ws_size,
                              hipStream_t stream)
{
    const float* x  = (const float*)d_in[0];
    const float* Wq = (const float*)d_in[1];
    const float* bq = (const float*)d_in[2];
    const float* Wk = (const float*)d_in[3];
    const float* bk = (const float*)d_in[4];
    const float* Wv = (const float*)d_in[5];
    const float* bv = (const float*)d_in[6];
    const float* Wo = (const float*)d_in[7];
    const float* bo = (const float*)d_in[8];
    float* out = (float*)d_out;

    size_t off = 0;
    auto alloc = [&](size_t bytes) {
        char* p = (char*)d_ws + off;
        off += (bytes + 255) & ~(size_t)255;
        return (void*)p;
    };
    unsigned short* qb  = (unsigned short*)alloc((size_t)NM * NH * 2);
    unsigned short* kb  = (unsigned short*)alloc((size_t)NM * NH * 2);
    unsigned short* vtb = (unsigned short*)alloc((size_t)NM * NH * 2);
    unsigned short* Wb  = (unsigned short*)alloc((size_t)192 * ND * 2);
    unsigned short* Wob = (unsigned short*)alloc((size_t)64 * 64 * 2);
    float* biasb = (float*)alloc(192 * 4);
    const size_t base = off;

    // KV-chunk size: prefer CT=8 (640 blocks), fall back if ws is tight.
    int ctLog = 5, MAXC = 1;
    const int cands[3] = {3, 4, 5};
    for (int ci = 0; ci < 3; ++ci) {
        const int cl = cands[ci];
        const int mc = (31 >> cl) + 1;
        const size_t nslot = (size_t)256 * mc;
        const size_t need = base + nslot * (4096 + 64) * 4 + 8192;
        if (need <= ws_size) { ctLog = cl; MAXC = mc; break; }
    }
    const size_t NSLOT = (size_t)256 * MAXC;
    float* Opart = (float*)alloc(NSLOT * 4096 * 4);
    float* lpart = (float*)alloc(NSLOT * 64 * 4);

    const int CT = 1 << ctLog;
    int NCperB = 0;
    for (int qt = 0; qt < 32; ++qt) NCperB += (qt + CT) >> ctLog;

    convw_kernel<<<256, 256, 0, stream>>>(Wq, bq, Wk, bk, Wv, bv, Wo, Wb, Wob, biasb);
    qkv_kernel<<<2 * (NM / 64), 512, 0, stream>>>(x, Wb, biasb, qb, kb, vtb);
    attn_kernel<<<8 * NCperB, 256, 0, stream>>>(qb, kb, vtb, Opart, lpart, ctLog, MAXC);
    combine_kernel<<<256, 256, 0, stream>>>(Opart, lpart, Wob, bo, out, ctLog, MAXC);
}

// Round 13
// 50.137 us; speedup vs baseline: 4.7125x; 1.1382x over previous
//
#include <hip/hip_runtime.h>
#include <hip/hip_bf16.h>

#define NB 8
#define NS 2048
#define ND 1024
#define NH 64
#define NM (NB*NS)   // 16384 rows

typedef __attribute__((ext_vector_type(8))) short short8;
typedef __attribute__((ext_vector_type(4))) short short4v;
typedef __attribute__((ext_vector_type(4))) float f32x4;
typedef __attribute__((ext_vector_type(4))) float f4;

// q pre-scale: fold 1/sqrt(64) and log2(e) so attention uses exp2 directly.
#define QSCALE (0.125f * 1.44269504088896340736f)

__device__ __forceinline__ unsigned short f2bf(float f) {
    union { __hip_bfloat16 h; unsigned short u; } cv;
    cv.h = __float2bfloat16(f);   // HW RTNE convert
    return cv.u;
}

// Barrier WITHOUT the vmcnt(0) drain __syncthreads would emit: drain only
// LDS ops (lgkm) so cross-wave LDS data is visible, but let prefetched
// global loads stay in flight across the barrier (T4: never vmcnt(0) in
// the main loop). Compiler fences prevent hoist/sink around it.
__device__ __forceinline__ void barrier_nd() {
    asm volatile("s_waitcnt lgkmcnt(0)" ::: "memory");
    __builtin_amdgcn_s_barrier();
    asm volatile("" ::: "memory");
}

// ---------------------------------------------------------------------------
// Kernel 0: weights -> bf16. Rows 0..63 Wq (pre-scaled), 64..127 Wk,
// 128..191 Wv (row-major [row][k]); plus Wob (bf16 Wo) and biasb.
// ---------------------------------------------------------------------------
__global__ __launch_bounds__(256) void convw_kernel(
    const float* __restrict__ Wq, const float* __restrict__ bq,
    const float* __restrict__ Wk, const float* __restrict__ bk,
    const float* __restrict__ Wv, const float* __restrict__ bv,
    const float* __restrict__ Wo,
    unsigned short* __restrict__ Wb, unsigned short* __restrict__ Wob,
    float* __restrict__ biasb)
{
    const int row = blockIdx.x;   // 0..255
    const int t = threadIdx.x;    // 0..255
    if (row < 192) {
        const float* W = row < 64 ? Wq : (row < 128 ? Wk : Wv);
        const float sc = row < 64 ? QSCALE : 1.0f;
        f4 v = *(const f4*)&W[(size_t)(row & 63) * ND + t * 4];
        short4v o;
#pragma unroll
        for (int j = 0; j < 4; ++j) o[j] = (short)f2bf(v[j] * sc);
        *(short4v*)&Wb[(size_t)row * ND + t * 4] = o;
        if (row == 0 && t < 192) {
            const float* bsrc = t < 64 ? bq : (t < 128 ? bk : bv);
            biasb[t] = bsrc[t & 63] * (t < 64 ? QSCALE : 1.0f);
        }
    } else if (t < 16) {
        f4 v = *(const f4*)&Wo[(size_t)(row - 192) * 64 + t * 4];
        short4v o;
#pragma unroll
        for (int j = 0; j < 4; ++j) o[j] = (short)f2bf(v[j]);
        *(short4v*)&Wob[(size_t)(row - 192) * 64 + t * 4] = o;
    }
}

// ---------------------------------------------------------------------------
// Kernel 1: QKV projection (R7 structure; in-loop barriers -> barrier_nd).
// 64 rows x 192 cols, BK=64, 8 waves, LDS dbuf, 2-deep register prefetch.
// V stored transposed [b][h][s].
// ---------------------------------------------------------------------------
__global__ __launch_bounds__(512, 2) void qkv_kernel(
    const float* __restrict__ x, const unsigned short* __restrict__ Wb,
    const float* __restrict__ biasb,
    unsigned short* __restrict__ q, unsigned short* __restrict__ k,
    unsigned short* __restrict__ vT)
{
    __shared__ unsigned short As[2][64 * 64];
    __shared__ unsigned short Bs[2][192 * 64];

    const int t = threadIdx.x;
    const int lane = t & 63, g = lane >> 4, li = lane & 15;
    const int w = t >> 6, rg = w >> 2, cg = w & 3;
    const int m0 = blockIdx.x * 64;
    const int arow = t >> 3, ach = t & 7;

    f32x4 acc[2][3];
#pragma unroll
    for (int a = 0; a < 2; ++a)
#pragma unroll
        for (int nf = 0; nf < 3; ++nf) acc[a][nf] = (f32x4)0.f;

    f4 xa[2][2]; short8 wr[2][3];

#define QKV_LOAD(KS, SL)                                                          \
    {                                                                             \
        const float* p_ = &x[(size_t)(m0 + arow) * ND + (KS) * 64 + ach * 8];     \
        xa[SL][0] = *(const f4*)p_; xa[SL][1] = *(const f4*)(p_ + 4);             \
        wr[SL][0] = *(const short8*)&Wb[(size_t)(t >> 3) * ND + (KS) * 64 + (t & 7) * 8];                  \
        wr[SL][1] = *(const short8*)&Wb[(size_t)((t + 512) >> 3) * ND + (KS) * 64 + ((t + 512) & 7) * 8];  \
        wr[SL][2] = *(const short8*)&Wb[(size_t)((t + 1024) >> 3) * ND + (KS) * 64 + ((t + 1024) & 7) * 8];\
    }

#define QKV_COMMIT(SL, BUF)                                                       \
    {                                                                             \
        short8 av_;                                                               \
        for (int j_ = 0; j_ < 4; ++j_) {                                          \
            av_[j_] = (short)f2bf(xa[SL][0][j_]);                                 \
            av_[j_ + 4] = (short)f2bf(xa[SL][1][j_]);                             \
        }                                                                         \
        *(short8*)&As[BUF][arow * 64 + ((ach ^ (arow & 7)) << 3)] = av_;          \
        int r0_ = t >> 3, c0_ = t & 7;                                            \
        *(short8*)&Bs[BUF][r0_ * 64 + ((c0_ ^ (r0_ & 7)) << 3)] = wr[SL][0];      \
        int r1_ = (t + 512) >> 3, c1_ = (t + 512) & 7;                            \
        *(short8*)&Bs[BUF][r1_ * 64 + ((c1_ ^ (r1_ & 7)) << 3)] = wr[SL][1];      \
        int r2_ = (t + 1024) >> 3, c2_ = (t + 1024) & 7;                          \
        *(short8*)&Bs[BUF][r2_ * 64 + ((c2_ ^ (r2_ & 7)) << 3)] = wr[SL][2];      \
    }

    QKV_LOAD(0, 0);
    QKV_LOAD(1, 1);
    QKV_COMMIT(0, 0);
    barrier_nd();

#pragma unroll
    for (int ks = 0; ks < 16; ++ks) {
        const int cur = ks & 1;
        if (ks < 14) QKV_LOAD(ks + 2, cur);
#pragma unroll
        for (int h = 0; h < 2; ++h) {
            short8 af0 = *(const short8*)&As[cur][(rg * 32 + 0 + li) * 64 + (((g + 4 * h) ^ (li & 7)) << 3)];
            short8 af1 = *(const short8*)&As[cur][(rg * 32 + 16 + li) * 64 + (((g + 4 * h) ^ (li & 7)) << 3)];
#pragma unroll
            for (int nf = 0; nf < 3; ++nf) {
                short8 bf = *(const short8*)&Bs[cur][(cg * 48 + nf * 16 + li) * 64 + (((g + 4 * h) ^ (li & 7)) << 3)];
                acc[0][nf] = __builtin_amdgcn_mfma_f32_16x16x32_bf16(af0, bf, acc[0][nf], 0, 0, 0);
                acc[1][nf] = __builtin_amdgcn_mfma_f32_16x16x32_bf16(af1, bf, acc[1][nf], 0, 0, 0);
            }
        }
        if (ks < 15) QKV_COMMIT((ks + 1) & 1, cur ^ 1);
        barrier_nd();
    }

    // epilogue: bias + store (q,k row-major; v transposed [b][h][s])
#pragma unroll
    for (int nf = 0; nf < 3; ++nf) {
        const int col = cg * 48 + nf * 16 + li;
        const float bias = biasb[col];
#pragma unroll
        for (int a = 0; a < 2; ++a) {
            const int row0 = m0 + rg * 32 + a * 16 + 4 * g;
            if (col < 64) {
#pragma unroll
                for (int i = 0; i < 4; ++i)
                    q[(size_t)(row0 + i) * NH + col] = f2bf(acc[a][nf][i] + bias);
            } else if (col < 128) {
#pragma unroll
                for (int i = 0; i < 4; ++i)
                    k[(size_t)(row0 + i) * NH + (col - 64)] = f2bf(acc[a][nf][i] + bias);
            } else {
                short4v pk;
#pragma unroll
                for (int i = 0; i < 4; ++i) pk[i] = (short)f2bf(acc[a][nf][i] + bias);
                const int bb = row0 >> 11, s = row0 & 2047;
                *(short4v*)&vT[(size_t)(bb * NH + (col - 128)) * NS + s] = pk;
            }
        }
    }
}

// ---------------------------------------------------------------------------
// Kernel 2: split-KV causal attention (R7; in-loop barriers -> barrier_nd).
// ---------------------------------------------------------------------------
__global__ __launch_bounds__(256, 2) void attn_kernel(
    const unsigned short* __restrict__ q, const unsigned short* __restrict__ k,
    const unsigned short* __restrict__ vT,
    float* __restrict__ Opart, float* __restrict__ lpart,
    int ctLog, int MAXC)
{
    __shared__ unsigned short Ks[2][64 * 64];
    __shared__ unsigned short Vs[2][64 * 64];
    __shared__ unsigned short Ps[4][16 * 64];

    const int t = threadIdx.x;
    const int w = t >> 6, lane = t & 63, g = lane >> 4, li = lane & 15;
    const int b = blockIdx.x & 7;          // batch -> XCD pinning
    const int pid = blockIdx.x >> 3;
    const int CT = 1 << ctLog;

    int qt = 0, c = 0;
    {
        int acc = 0;
        for (int u = 31; u >= 0; --u) {    // largest-work-first
            int nch = (u + CT) >> ctLog;
            if (pid < acc + nch) { qt = u; c = pid - acc; break; }
            acc += nch;
        }
    }
    const int t0 = c * CT;
    const int rem = qt + 1 - t0;
    const int tcount = rem < CT ? rem : CT;

    const size_t qkbase = (size_t)b * NS * NH;
    const int qrow = qt * 64 + w * 16 + li;
    const short8 qa0 = *(const short8*)&q[qkbase + (size_t)qrow * NH + g * 8];
    const short8 qa1 = *(const short8*)&q[qkbase + (size_t)qrow * NH + 32 + g * 8];

    float l_i[4]; f32x4 oacc[4];
#pragma unroll
    for (int i = 0; i < 4; ++i) { l_i[i] = 0.f; oacc[i] = (f32x4)0.f; }

    const int srow = t >> 3, sch = t & 7;
    short8 kreg0, kreg1, vreg0, vreg1;

    {
        const int kv0 = t0 * 64;
        kreg0 = *(const short8*)&k[qkbase + (size_t)(kv0 + srow) * NH + sch * 8];
        kreg1 = *(const short8*)&k[qkbase + (size_t)(kv0 + srow + 32) * NH + sch * 8];
        vreg0 = *(const short8*)&vT[(size_t)(b * NH + srow) * NS + kv0 + sch * 8];
        vreg1 = *(const short8*)&vT[(size_t)(b * NH + srow + 32) * NS + kv0 + sch * 8];
        *(short8*)&Ks[0][srow * 64 + ((sch ^ (srow & 7)) << 3)] = kreg0;
        *(short8*)&Ks[0][(srow + 32) * 64 + ((sch ^ (srow & 7)) << 3)] = kreg1;
        *(short8*)&Vs[0][srow * 64 + ((sch ^ (srow & 7)) << 3)] = vreg0;
        *(short8*)&Vs[0][(srow + 32) * 64 + ((sch ^ (srow & 7)) << 3)] = vreg1;
    }
    barrier_nd();

    for (int tt = 0; tt < tcount; ++tt) {
        const int cur = tt & 1;
        const int kv0 = (t0 + tt) * 64;
        if (tt + 1 < tcount) {   // issue next-tile loads early (T14)
            const int nv0 = kv0 + 64;
            kreg0 = *(const short8*)&k[qkbase + (size_t)(nv0 + srow) * NH + sch * 8];
            kreg1 = *(const short8*)&k[qkbase + (size_t)(nv0 + srow + 32) * NH + sch * 8];
            vreg0 = *(const short8*)&vT[(size_t)(b * NH + srow) * NS + nv0 + sch * 8];
            vreg1 = *(const short8*)&vT[(size_t)(b * NH + srow + 32) * NS + nv0 + sch * 8];
        }
        // ---- QK^T: 16 q x 64 kv (scores already in log2 domain) ----
        f32x4 s[4];
#pragma unroll
        for (int c4 = 0; c4 < 4; ++c4) {
            s[c4] = (f32x4)0.f;
            const int krow = 16 * c4 + li;
            short8 kf0 = *(const short8*)&Ks[cur][krow * 64 + ((g ^ (li & 7)) << 3)];
            s[c4] = __builtin_amdgcn_mfma_f32_16x16x32_bf16(qa0, kf0, s[c4], 0, 0, 0);
            short8 kf1 = *(const short8*)&Ks[cur][krow * 64 + (((g + 4) ^ (li & 7)) << 3)];
            s[c4] = __builtin_amdgcn_mfma_f32_16x16x32_bf16(qa1, kf1, s[c4], 0, 0, 0);
        }
        // ---- causal mask: only the diagonal tile ----
        if (kv0 == qt * 64) {
#pragma unroll
            for (int c4 = 0; c4 < 4; ++c4)
#pragma unroll
                for (int i = 0; i < 4; ++i)
                    if (16 * c4 + li > w * 16 + 4 * g + i) s[c4][i] = -1e30f;
        }
        // ---- no-max softmax: p = exp2(min(s,80)), defer row-sum reduce ----
        float p[4][4];
#pragma unroll
        for (int c4 = 0; c4 < 4; ++c4)
#pragma unroll
            for (int i = 0; i < 4; ++i)
                p[c4][i] = exp2f(fminf(s[c4][i], 80.f));
#pragma unroll
        for (int i = 0; i < 4; ++i)
            l_i[i] += (p[0][i] + p[1][i]) + (p[2][i] + p[3][i]);

        // ---- P -> per-wave LDS (swizzled), then PV ----
#pragma unroll
        for (int c4 = 0; c4 < 4; ++c4)
#pragma unroll
            for (int i = 0; i < 4; ++i) {
                const int prow = 4 * g + i;
                const int chunk = 2 * c4 + (li >> 3);
                Ps[w][prow * 64 + ((chunk ^ (prow & 7)) << 3) + (li & 7)] = f2bf(p[c4][i]);
            }
        short8 pf0 = *(const short8*)&Ps[w][li * 64 + ((g ^ (li & 7)) << 3)];
        short8 pf1 = *(const short8*)&Ps[w][li * 64 + (((g + 4) ^ (li & 7)) << 3)];
#pragma unroll
        for (int nf = 0; nf < 4; ++nf) {
            const int vrow = nf * 16 + li;
            short8 vf0 = *(const short8*)&Vs[cur][vrow * 64 + ((g ^ (li & 7)) << 3)];
            short8 vf1 = *(const short8*)&Vs[cur][vrow * 64 + (((g + 4) ^ (li & 7)) << 3)];
            oacc[nf] = __builtin_amdgcn_mfma_f32_16x16x32_bf16(pf0, vf0, oacc[nf], 0, 0, 0);
            oacc[nf] = __builtin_amdgcn_mfma_f32_16x16x32_bf16(pf1, vf1, oacc[nf], 0, 0, 0);
        }
        if (tt + 1 < tcount) {   // commit next tile late
            *(short8*)&Ks[cur ^ 1][srow * 64 + ((sch ^ (srow & 7)) << 3)] = kreg0;
            *(short8*)&Ks[cur ^ 1][(srow + 32) * 64 + ((sch ^ (srow & 7)) << 3)] = kreg1;
            *(short8*)&Vs[cur ^ 1][srow * 64 + ((sch ^ (srow & 7)) << 3)] = vreg0;
            *(short8*)&Vs[cur ^ 1][(srow + 32) * 64 + ((sch ^ (srow & 7)) << 3)] = vreg1;
        }
        barrier_nd();
    }

    // ---- one cross-lane l reduction per block ----
#pragma unroll
    for (int off = 1; off < 16; off <<= 1)
#pragma unroll
        for (int i = 0; i < 4; ++i) l_i[i] += __shfl_xor(l_i[i], off);

    const size_t slot = (size_t)((b * 32 + qt) * MAXC + c);
    float* Op = Opart + slot * 4096;
#pragma unroll
    for (int nf = 0; nf < 4; ++nf)
#pragma unroll
        for (int i = 0; i < 4; ++i)
            Op[(w * 16 + 4 * g + i) * 64 + nf * 16 + li] = oacc[nf][i];
    if (li == 0) {
#pragma unroll
        for (int i = 0; i < 4; ++i)
            lpart[slot * 64 + w * 16 + 4 * g + i] = l_i[i];
    }
}

// ---------------------------------------------------------------------------
// Kernel 3: combine partials + MFMA output projection (out = O @ Wo^T + bo)
// ---------------------------------------------------------------------------
__global__ __launch_bounds__(256, 2) void combine_kernel(
    const float* __restrict__ Opart, const float* __restrict__ lpart,
    const unsigned short* __restrict__ Wob, const float* __restrict__ bo,
    float* __restrict__ out, int ctLog, int MAXC)
{
    __shared__ unsigned short Osm[64 * 64];
    __shared__ float Linv[64];

    const int t = threadIdx.x;
    const int b = blockIdx.x & 7, qt = blockIdx.x >> 3;   // XCD-pinned to attn
    const int CT = 1 << ctLog;
    const int nch = (qt + CT) >> ctLog;
    const size_t base_slot = (size_t)(b * 32 + qt) * MAXC;

    if (t < 64) {
        float L = 0.f;
        for (int cc = 0; cc < nch; ++cc)
            L += lpart[(base_slot + cc) * 64 + t];
        Linv[t] = 1.f / L;
    }

    // accumulate O' across chunks: thread owns row r, 16 cols
    const int r = t >> 2, c0 = (t & 3) * 16;
    f4 a0 = (f4)0.f, a1 = (f4)0.f, a2 = (f4)0.f, a3 = (f4)0.f;
    for (int cc = 0; cc < nch; ++cc) {
        const float* P = Opart + (base_slot + cc) * 4096 + r * 64 + c0;
        a0 += *(const f4*)P; a1 += *(const f4*)(P + 4);
        a2 += *(const f4*)(P + 8); a3 += *(const f4*)(P + 12);
    }
    __syncthreads();
    {
        const float sc = Linv[r];
        short8 o0, o1;
#pragma unroll
        for (int j = 0; j < 4; ++j) {
            o0[j] = (short)f2bf(a0[j] * sc); o0[j + 4] = (short)f2bf(a1[j] * sc);
            o1[j] = (short)f2bf(a2[j] * sc); o1[j + 4] = (short)f2bf(a3[j] * sc);
        }
        const int ch0 = (t & 3) * 2;
        *(short8*)&Osm[r * 64 + ((ch0 ^ (r & 7)) << 3)] = o0;
        *(short8*)&Osm[r * 64 + (((ch0 + 1) ^ (r & 7)) << 3)] = o1;
    }
    __syncthreads();

    // oproj: 4 waves x 16 rows, MFMA, B = Wo rows (bf16, L2)
    const int w = t >> 6, lane = t & 63, g = lane >> 4, li = lane & 15;
    f32x4 acc[4];
#pragma unroll
    for (int nf = 0; nf < 4; ++nf) acc[nf] = (f32x4)0.f;
#pragma unroll
    for (int s = 0; s < 2; ++s) {
        const int rr = w * 16 + li;
        short8 af = *(const short8*)&Osm[rr * 64 + (((g + 4 * s) ^ (rr & 7)) << 3)];
#pragma unroll
        for (int nf = 0; nf < 4; ++nf) {
            short8 bf = *(const short8*)&Wob[(size_t)(nf * 16 + li) * 64 + s * 32 + g * 8];
            acc[nf] = __builtin_amdgcn_mfma_f32_16x16x32_bf16(af, bf, acc[nf], 0, 0, 0);
        }
    }
#pragma unroll
    for (int nf = 0; nf < 4; ++nf) {
        const float bias = bo[nf * 16 + li];
#pragma unroll
        for (int i = 0; i < 4; ++i) {
            const size_t row = (size_t)b * NS + qt * 64 + w * 16 + 4 * g + i;
            out[row * 64 + nf * 16 + li] = acc[nf][i] + bias;
        }
    }
}

// ---------------------------------------------------------------------------
extern "C" void kernel_launch(void* const* d_in, const int* in_sizes, int n_in,
                              void* d_out, int out_size, void* d_ws, size_t ws_size,
                              hipStream_t stream)
{
    const float* x  = (const float*)d_in[0];
    const float* Wq = (const float*)d_in[1];
    const float* bq = (const float*)d_in[2];
    const float* Wk = (const float*)d_in[3];
    const float* bk = (const float*)d_in[4];
    const float* Wv = (const float*)d_in[5];
    const float* bv = (const float*)d_in[6];
    const float* Wo = (const float*)d_in[7];
    const float* bo = (const float*)d_in[8];
    float* out = (float*)d_out;

    size_t off = 0;
    auto alloc = [&](size_t bytes) {
        char* p = (char*)d_ws + off;
        off += (bytes + 255) & ~(size_t)255;
        return (void*)p;
    };
    unsigned short* qb  = (unsigned short*)alloc((size_t)NM * NH * 2);
    unsigned short* kb  = (unsigned short*)alloc((size_t)NM * NH * 2);
    unsigned short* vtb = (unsigned short*)alloc((size_t)NM * NH * 2);
    unsigned short* Wb  = (unsigned short*)alloc((size_t)192 * ND * 2);
    unsigned short* Wob = (unsigned short*)alloc((size_t)64 * 64 * 2);
    float* biasb = (float*)alloc(192 * 4);
    const size_t base = off;

    // KV-chunk size: prefer CT=8 (640 blocks), fall back if ws is tight.
    int ctLog = 5, MAXC = 1;
    const int cands[3] = {3, 4, 5};
    for (int ci = 0; ci < 3; ++ci) {
        const int cl = cands[ci];
        const int mc = (31 >> cl) + 1;
        const size_t nslot = (size_t)256 * mc;
        const size_t need = base + nslot * (4096 + 64) * 4 + 8192;
        if (need <= ws_size) { ctLog = cl; MAXC = mc; break; }
    }
    const size_t NSLOT = (size_t)256 * MAXC;
    float* Opart = (float*)alloc(NSLOT * 4096 * 4);
    float* lpart = (float*)alloc(NSLOT * 64 * 4);

    const int CT = 1 << ctLog;
    int NCperB = 0;
    for (int qt = 0; qt < 32; ++qt) NCperB += (qt + CT) >> ctLog;

    convw_kernel<<<256, 256, 0, stream>>>(Wq, bq, Wk, bk, Wv, bv, Wo, Wb, Wob, biasb);
    qkv_kernel<<<NM / 64, 512, 0, stream>>>(x, Wb, biasb, qb, kb, vtb);
    attn_kernel<<<8 * NCperB, 256, 0, stream>>>(qb, kb, vtb, Opart, lpart, ctLog, MAXC);
    combine_kernel<<<256, 256, 0, stream>>>(Opart, lpart, Wob, bo, out, ctLog, MAXC);
}

// Round 14
// 48.450 us; speedup vs baseline: 4.8767x; 1.0348x over previous
//
#include <hip/hip_runtime.h>
#include <hip/hip_bf16.h>

#define NB 8
#define NS 2048
#define ND 1024
#define NH 64
#define NM (NB*NS)   // 16384 rows

typedef __attribute__((ext_vector_type(8))) short short8;
typedef __attribute__((ext_vector_type(4))) short short4v;
typedef __attribute__((ext_vector_type(4))) float f32x4;
typedef __attribute__((ext_vector_type(4))) float f4;

// q pre-scale: fold 1/sqrt(64) and log2(e) so attention uses exp2 directly.
#define QSCALE (0.125f * 1.44269504088896340736f)

__device__ __forceinline__ unsigned short f2bf(float f) {
    union { __hip_bfloat16 h; unsigned short u; } cv;
    cv.h = __float2bfloat16(f);   // HW RTNE convert
    return cv.u;
}

// Barrier WITHOUT the vmcnt(0) drain __syncthreads would emit.
__device__ __forceinline__ void barrier_nd() {
    asm volatile("s_waitcnt lgkmcnt(0)" ::: "memory");
    __builtin_amdgcn_s_barrier();
    asm volatile("" ::: "memory");
}

// ---------------------------------------------------------------------------
// Kernel 0: weights -> bf16. Rows 0..63 Wq (pre-scaled), 64..127 Wk,
// 128..191 Wv (row-major [row][k]); plus Wob (bf16 Wo) and biasb.
// ---------------------------------------------------------------------------
__global__ __launch_bounds__(256) void convw_kernel(
    const float* __restrict__ Wq, const float* __restrict__ bq,
    const float* __restrict__ Wk, const float* __restrict__ bk,
    const float* __restrict__ Wv, const float* __restrict__ bv,
    const float* __restrict__ Wo,
    unsigned short* __restrict__ Wb, unsigned short* __restrict__ Wob,
    float* __restrict__ biasb)
{
    const int row = blockIdx.x;   // 0..255
    const int t = threadIdx.x;    // 0..255
    if (row < 192) {
        const float* W = row < 64 ? Wq : (row < 128 ? Wk : Wv);
        const float sc = row < 64 ? QSCALE : 1.0f;
        f4 v = *(const f4*)&W[(size_t)(row & 63) * ND + t * 4];
        short4v o;
#pragma unroll
        for (int j = 0; j < 4; ++j) o[j] = (short)f2bf(v[j] * sc);
        *(short4v*)&Wb[(size_t)row * ND + t * 4] = o;
        if (row == 0 && t < 192) {
            const float* bsrc = t < 64 ? bq : (t < 128 ? bk : bv);
            biasb[t] = bsrc[t & 63] * (t < 64 ? QSCALE : 1.0f);
        }
    } else if (t < 16) {
        f4 v = *(const f4*)&Wo[(size_t)(row - 192) * 64 + t * 4];
        short4v o;
#pragma unroll
        for (int j = 0; j < 4; ++j) o[j] = (short)f2bf(v[j]);
        *(short4v*)&Wob[(size_t)(row - 192) * 64 + t * 4] = o;
    }
}

// ---------------------------------------------------------------------------
// Kernel 1: QKV projection. 64 rows x 192 cols, BK=64, 8 waves, LDS dbuf,
// *** 3-deep register prefetch *** : data committed at iter ks was issued
// at iter ks-2 (two full iterations of latency budget). Loop fully
// unrolled so all slot indices are compile-time constants.
// ---------------------------------------------------------------------------
__global__ __launch_bounds__(512, 2) void qkv_kernel(
    const float* __restrict__ x, const unsigned short* __restrict__ Wb,
    const float* __restrict__ biasb,
    unsigned short* __restrict__ q, unsigned short* __restrict__ k,
    unsigned short* __restrict__ vT)
{
    __shared__ unsigned short As[2][64 * 64];
    __shared__ unsigned short Bs[2][192 * 64];

    const int t = threadIdx.x;
    const int lane = t & 63, g = lane >> 4, li = lane & 15;
    const int w = t >> 6, rg = w >> 2, cg = w & 3;
    const int m0 = blockIdx.x * 64;
    const int arow = t >> 3, ach = t & 7;

    f32x4 acc[2][3];
#pragma unroll
    for (int a = 0; a < 2; ++a)
#pragma unroll
        for (int nf = 0; nf < 3; ++nf) acc[a][nf] = (f32x4)0.f;

    f4 xa[3][2]; short8 wr[3][3];   // 3 slots: issue->consume = 2 iters

#define QKV_LOAD(KS, SL)                                                          \
    {                                                                             \
        const float* p_ = &x[(size_t)(m0 + arow) * ND + (KS) * 64 + ach * 8];     \
        xa[SL][0] = *(const f4*)p_; xa[SL][1] = *(const f4*)(p_ + 4);             \
        wr[SL][0] = *(const short8*)&Wb[(size_t)(t >> 3) * ND + (KS) * 64 + (t & 7) * 8];                  \
        wr[SL][1] = *(const short8*)&Wb[(size_t)((t + 512) >> 3) * ND + (KS) * 64 + ((t + 512) & 7) * 8];  \
        wr[SL][2] = *(const short8*)&Wb[(size_t)((t + 1024) >> 3) * ND + (KS) * 64 + ((t + 1024) & 7) * 8];\
    }

#define QKV_COMMIT(SL, BUF)                                                       \
    {                                                                             \
        short8 av_;                                                               \
        for (int j_ = 0; j_ < 4; ++j_) {                                          \
            av_[j_] = (short)f2bf(xa[SL][0][j_]);                                 \
            av_[j_ + 4] = (short)f2bf(xa[SL][1][j_]);                             \
        }                                                                         \
        *(short8*)&As[BUF][arow * 64 + ((ach ^ (arow & 7)) << 3)] = av_;          \
        int r0_ = t >> 3, c0_ = t & 7;                                            \
        *(short8*)&Bs[BUF][r0_ * 64 + ((c0_ ^ (r0_ & 7)) << 3)] = wr[SL][0];      \
        int r1_ = (t + 512) >> 3, c1_ = (t + 512) & 7;                            \
        *(short8*)&Bs[BUF][r1_ * 64 + ((c1_ ^ (r1_ & 7)) << 3)] = wr[SL][1];      \
        int r2_ = (t + 1024) >> 3, c2_ = (t + 1024) & 7;                          \
        *(short8*)&Bs[BUF][r2_ * 64 + ((c2_ ^ (r2_ & 7)) << 3)] = wr[SL][2];      \
    }

    QKV_LOAD(0, 0);
    QKV_LOAD(1, 1);
    QKV_LOAD(2, 2);
    QKV_COMMIT(0, 0);
    barrier_nd();

#pragma unroll
    for (int ks = 0; ks < 16; ++ks) {
        const int cur = ks & 1;
        if (ks < 13) QKV_LOAD(ks + 3, (ks + 3) % 3);
#pragma unroll
        for (int h = 0; h < 2; ++h) {
            short8 af0 = *(const short8*)&As[cur][(rg * 32 + 0 + li) * 64 + (((g + 4 * h) ^ (li & 7)) << 3)];
            short8 af1 = *(const short8*)&As[cur][(rg * 32 + 16 + li) * 64 + (((g + 4 * h) ^ (li & 7)) << 3)];
#pragma unroll
            for (int nf = 0; nf < 3; ++nf) {
                short8 bf = *(const short8*)&Bs[cur][(cg * 48 + nf * 16 + li) * 64 + (((g + 4 * h) ^ (li & 7)) << 3)];
                acc[0][nf] = __builtin_amdgcn_mfma_f32_16x16x32_bf16(af0, bf, acc[0][nf], 0, 0, 0);
                acc[1][nf] = __builtin_amdgcn_mfma_f32_16x16x32_bf16(af1, bf, acc[1][nf], 0, 0, 0);
            }
        }
        if (ks < 15) QKV_COMMIT((ks + 1) % 3, cur ^ 1);
        barrier_nd();
    }

    // epilogue: bias + store (q,k row-major; v transposed [b][h][s])
#pragma unroll
    for (int nf = 0; nf < 3; ++nf) {
        const int col = cg * 48 + nf * 16 + li;
        const float bias = biasb[col];
#pragma unroll
        for (int a = 0; a < 2; ++a) {
            const int row0 = m0 + rg * 32 + a * 16 + 4 * g;
            if (col < 64) {
#pragma unroll
                for (int i = 0; i < 4; ++i)
                    q[(size_t)(row0 + i) * NH + col] = f2bf(acc[a][nf][i] + bias);
            } else if (col < 128) {
#pragma unroll
                for (int i = 0; i < 4; ++i)
                    k[(size_t)(row0 + i) * NH + (col - 64)] = f2bf(acc[a][nf][i] + bias);
            } else {
                short4v pk;
#pragma unroll
                for (int i = 0; i < 4; ++i) pk[i] = (short)f2bf(acc[a][nf][i] + bias);
                const int bb = row0 >> 11, s = row0 & 2047;
                *(short4v*)&vT[(size_t)(bb * NH + (col - 128)) * NS + s] = pk;
            }
        }
    }
}

// ---------------------------------------------------------------------------
// Kernel 2: split-KV causal attention (R13, unchanged).
// ---------------------------------------------------------------------------
__global__ __launch_bounds__(256, 2) void attn_kernel(
    const unsigned short* __restrict__ q, const unsigned short* __restrict__ k,
    const unsigned short* __restrict__ vT,
    float* __restrict__ Opart, float* __restrict__ lpart,
    int ctLog, int MAXC)
{
    __shared__ unsigned short Ks[2][64 * 64];
    __shared__ unsigned short Vs[2][64 * 64];
    __shared__ unsigned short Ps[4][16 * 64];

    const int t = threadIdx.x;
    const int w = t >> 6, lane = t & 63, g = lane >> 4, li = lane & 15;
    const int b = blockIdx.x & 7;          // batch -> XCD pinning
    const int pid = blockIdx.x >> 3;
    const int CT = 1 << ctLog;

    int qt = 0, c = 0;
    {
        int acc = 0;
        for (int u = 31; u >= 0; --u) {    // largest-work-first
            int nch = (u + CT) >> ctLog;
            if (pid < acc + nch) { qt = u; c = pid - acc; break; }
            acc += nch;
        }
    }
    const int t0 = c * CT;
    const int rem = qt + 1 - t0;
    const int tcount = rem < CT ? rem : CT;

    const size_t qkbase = (size_t)b * NS * NH;
    const int qrow = qt * 64 + w * 16 + li;
    const short8 qa0 = *(const short8*)&q[qkbase + (size_t)qrow * NH + g * 8];
    const short8 qa1 = *(const short8*)&q[qkbase + (size_t)qrow * NH + 32 + g * 8];

    float l_i[4]; f32x4 oacc[4];
#pragma unroll
    for (int i = 0; i < 4; ++i) { l_i[i] = 0.f; oacc[i] = (f32x4)0.f; }

    const int srow = t >> 3, sch = t & 7;
    short8 kreg0, kreg1, vreg0, vreg1;

    {
        const int kv0 = t0 * 64;
        kreg0 = *(const short8*)&k[qkbase + (size_t)(kv0 + srow) * NH + sch * 8];
        kreg1 = *(const short8*)&k[qkbase + (size_t)(kv0 + srow + 32) * NH + sch * 8];
        vreg0 = *(const short8*)&vT[(size_t)(b * NH + srow) * NS + kv0 + sch * 8];
        vreg1 = *(const short8*)&vT[(size_t)(b * NH + srow + 32) * NS + kv0 + sch * 8];
        *(short8*)&Ks[0][srow * 64 + ((sch ^ (srow & 7)) << 3)] = kreg0;
        *(short8*)&Ks[0][(srow + 32) * 64 + ((sch ^ (srow & 7)) << 3)] = kreg1;
        *(short8*)&Vs[0][srow * 64 + ((sch ^ (srow & 7)) << 3)] = vreg0;
        *(short8*)&Vs[0][(srow + 32) * 64 + ((sch ^ (srow & 7)) << 3)] = vreg1;
    }
    barrier_nd();

    for (int tt = 0; tt < tcount; ++tt) {
        const int cur = tt & 1;
        const int kv0 = (t0 + tt) * 64;
        if (tt + 1 < tcount) {   // issue next-tile loads early (T14)
            const int nv0 = kv0 + 64;
            kreg0 = *(const short8*)&k[qkbase + (size_t)(nv0 + srow) * NH + sch * 8];
            kreg1 = *(const short8*)&k[qkbase + (size_t)(nv0 + srow + 32) * NH + sch * 8];
            vreg0 = *(const short8*)&vT[(size_t)(b * NH + srow) * NS + nv0 + sch * 8];
            vreg1 = *(const short8*)&vT[(size_t)(b * NH + srow + 32) * NS + nv0 + sch * 8];
        }
        // ---- QK^T: 16 q x 64 kv (scores already in log2 domain) ----
        f32x4 s[4];
#pragma unroll
        for (int c4 = 0; c4 < 4; ++c4) {
            s[c4] = (f32x4)0.f;
            const int krow = 16 * c4 + li;
            short8 kf0 = *(const short8*)&Ks[cur][krow * 64 + ((g ^ (li & 7)) << 3)];
            s[c4] = __builtin_amdgcn_mfma_f32_16x16x32_bf16(qa0, kf0, s[c4], 0, 0, 0);
            short8 kf1 = *(const short8*)&Ks[cur][krow * 64 + (((g + 4) ^ (li & 7)) << 3)];
            s[c4] = __builtin_amdgcn_mfma_f32_16x16x32_bf16(qa1, kf1, s[c4], 0, 0, 0);
        }
        // ---- causal mask: only the diagonal tile ----
        if (kv0 == qt * 64) {
#pragma unroll
            for (int c4 = 0; c4 < 4; ++c4)
#pragma unroll
                for (int i = 0; i < 4; ++i)
                    if (16 * c4 + li > w * 16 + 4 * g + i) s[c4][i] = -1e30f;
        }
        // ---- no-max softmax: p = exp2(min(s,80)), defer row-sum reduce ----
        float p[4][4];
#pragma unroll
        for (int c4 = 0; c4 < 4; ++c4)
#pragma unroll
            for (int i = 0; i < 4; ++i)
                p[c4][i] = exp2f(fminf(s[c4][i], 80.f));
#pragma unroll
        for (int i = 0; i < 4; ++i)
            l_i[i] += (p[0][i] + p[1][i]) + (p[2][i] + p[3][i]);

        // ---- P -> per-wave LDS (swizzled), then PV ----
#pragma unroll
        for (int c4 = 0; c4 < 4; ++c4)
#pragma unroll
            for (int i = 0; i < 4; ++i) {
                const int prow = 4 * g + i;
                const int chunk = 2 * c4 + (li >> 3);
                Ps[w][prow * 64 + ((chunk ^ (prow & 7)) << 3) + (li & 7)] = f2bf(p[c4][i]);
            }
        short8 pf0 = *(const short8*)&Ps[w][li * 64 + ((g ^ (li & 7)) << 3)];
        short8 pf1 = *(const short8*)&Ps[w][li * 64 + (((g + 4) ^ (li & 7)) << 3)];
#pragma unroll
        for (int nf = 0; nf < 4; ++nf) {
            const int vrow = nf * 16 + li;
            short8 vf0 = *(const short8*)&Vs[cur][vrow * 64 + ((g ^ (li & 7)) << 3)];
            short8 vf1 = *(const short8*)&Vs[cur][vrow * 64 + (((g + 4) ^ (li & 7)) << 3)];
            oacc[nf] = __builtin_amdgcn_mfma_f32_16x16x32_bf16(pf0, vf0, oacc[nf], 0, 0, 0);
            oacc[nf] = __builtin_amdgcn_mfma_f32_16x16x32_bf16(pf1, vf1, oacc[nf], 0, 0, 0);
        }
        if (tt + 1 < tcount) {   // commit next tile late
            *(short8*)&Ks[cur ^ 1][srow * 64 + ((sch ^ (srow & 7)) << 3)] = kreg0;
            *(short8*)&Ks[cur ^ 1][(srow + 32) * 64 + ((sch ^ (srow & 7)) << 3)] = kreg1;
            *(short8*)&Vs[cur ^ 1][srow * 64 + ((sch ^ (srow & 7)) << 3)] = vreg0;
            *(short8*)&Vs[cur ^ 1][(srow + 32) * 64 + ((sch ^ (srow & 7)) << 3)] = vreg1;
        }
        barrier_nd();
    }

    // ---- one cross-lane l reduction per block ----
#pragma unroll
    for (int off = 1; off < 16; off <<= 1)
#pragma unroll
        for (int i = 0; i < 4; ++i) l_i[i] += __shfl_xor(l_i[i], off);

    const size_t slot = (size_t)((b * 32 + qt) * MAXC + c);
    float* Op = Opart + slot * 4096;
#pragma unroll
    for (int nf = 0; nf < 4; ++nf)
#pragma unroll
        for (int i = 0; i < 4; ++i)
            Op[(w * 16 + 4 * g + i) * 64 + nf * 16 + li] = oacc[nf][i];
    if (li == 0) {
#pragma unroll
        for (int i = 0; i < 4; ++i)
            lpart[slot * 64 + w * 16 + 4 * g + i] = l_i[i];
    }
}

// ---------------------------------------------------------------------------
// Kernel 3: combine partials + MFMA output projection (out = O @ Wo^T + bo)
// ---------------------------------------------------------------------------
__global__ __launch_bounds__(256, 2) void combine_kernel(
    const float* __restrict__ Opart, const float* __restrict__ lpart,
    const unsigned short* __restrict__ Wob, const float* __restrict__ bo,
    float* __restrict__ out, int ctLog, int MAXC)
{
    __shared__ unsigned short Osm[64 * 64];
    __shared__ float Linv[64];

    const int t = threadIdx.x;
    const int b = blockIdx.x & 7, qt = blockIdx.x >> 3;   // XCD-pinned to attn
    const int CT = 1 << ctLog;
    const int nch = (qt + CT) >> ctLog;
    const size_t base_slot = (size_t)(b * 32 + qt) * MAXC;

    if (t < 64) {
        float L = 0.f;
        for (int cc = 0; cc < nch; ++cc)
            L += lpart[(base_slot + cc) * 64 + t];
        Linv[t] = 1.f / L;
    }

    // accumulate O' across chunks: thread owns row r, 16 cols
    const int r = t >> 2, c0 = (t & 3) * 16;
    f4 a0 = (f4)0.f, a1 = (f4)0.f, a2 = (f4)0.f, a3 = (f4)0.f;
    for (int cc = 0; cc < nch; ++cc) {
        const float* P = Opart + (base_slot + cc) * 4096 + r * 64 + c0;
        a0 += *(const f4*)P; a1 += *(const f4*)(P + 4);
        a2 += *(const f4*)(P + 8); a3 += *(const f4*)(P + 12);
    }
    __syncthreads();
    {
        const float sc = Linv[r];
        short8 o0, o1;
#pragma unroll
        for (int j = 0; j < 4; ++j) {
            o0[j] = (short)f2bf(a0[j] * sc); o0[j + 4] = (short)f2bf(a1[j] * sc);
            o1[j] = (short)f2bf(a2[j] * sc); o1[j + 4] = (short)f2bf(a3[j] * sc);
        }
        const int ch0 = (t & 3) * 2;
        *(short8*)&Osm[r * 64 + ((ch0 ^ (r & 7)) << 3)] = o0;
        *(short8*)&Osm[r * 64 + (((ch0 + 1) ^ (r & 7)) << 3)] = o1;
    }
    __syncthreads();

    // oproj: 4 waves x 16 rows, MFMA, B = Wo rows (bf16, L2)
    const int w = t >> 6, lane = t & 63, g = lane >> 4, li = lane & 15;
    f32x4 acc[4];
#pragma unroll
    for (int nf = 0; nf < 4; ++nf) acc[nf] = (f32x4)0.f;
#pragma unroll
    for (int s = 0; s < 2; ++s) {
        const int rr = w * 16 + li;
        short8 af = *(const short8*)&Osm[rr * 64 + (((g + 4 * s) ^ (rr & 7)) << 3)];
#pragma unroll
        for (int nf = 0; nf < 4; ++nf) {
            short8 bf = *(const short8*)&Wob[(size_t)(nf * 16 + li) * 64 + s * 32 + g * 8];
            acc[nf] = __builtin_amdgcn_mfma_f32_16x16x32_bf16(af, bf, acc[nf], 0, 0, 0);
        }
    }
#pragma unroll
    for (int nf = 0; nf < 4; ++nf) {
        const float bias = bo[nf * 16 + li];
#pragma unroll
        for (int i = 0; i < 4; ++i) {
            const size_t row = (size_t)b * NS + qt * 64 + w * 16 + 4 * g + i;
            out[row * 64 + nf * 16 + li] = acc[nf][i] + bias;
        }
    }
}

// ---------------------------------------------------------------------------
extern "C" void kernel_launch(void* const* d_in, const int* in_sizes, int n_in,
                              void* d_out, int out_size, void* d_ws, size_t ws_size,
                              hipStream_t stream)
{
    const float* x  = (const float*)d_in[0];
    const float* Wq = (const float*)d_in[1];
    const float* bq = (const float*)d_in[2];
    const float* Wk = (const float*)d_in[3];
    const float* bk = (const float*)d_in[4];
    const float* Wv = (const float*)d_in[5];
    const float* bv = (const float*)d_in[6];
    const float* Wo = (const float*)d_in[7];
    const float* bo = (const float*)d_in[8];
    float* out = (float*)d_out;

    size_t off = 0;
    auto alloc = [&](size_t bytes) {
        char* p = (char*)d_ws + off;
        off += (bytes + 255) & ~(size_t)255;
        return (void*)p;
    };
    unsigned short* qb  = (unsigned short*)alloc((size_t)NM * NH * 2);
    unsigned short* kb  = (unsigned short*)alloc((size_t)NM * NH * 2);
    unsigned short* vtb = (unsigned short*)alloc((size_t)NM * NH * 2);
    unsigned short* Wb  = (unsigned short*)alloc((size_t)192 * ND * 2);
    unsigned short* Wob = (unsigned short*)alloc((size_t)64 * 64 * 2);
    float* biasb = (float*)alloc(192 * 4);
    const size_t base = off;

    // KV-chunk size: prefer CT=8 (640 blocks), fall back if ws is tight.
    int ctLog = 5, MAXC = 1;
    const int cands[3] = {3, 4, 5};
    for (int ci = 0; ci < 3; ++ci) {
        const int cl = cands[ci];
        const int mc = (31 >> cl) + 1;
        const size_t nslot = (size_t)256 * mc;
        const size_t need = base + nslot * (4096 + 64) * 4 + 8192;
        if (need <= ws_size) { ctLog = cl; MAXC = mc; break; }
    }
    const size_t NSLOT = (size_t)256 * MAXC;
    float* Opart = (float*)alloc(NSLOT * 4096 * 4);
    float* lpart = (float*)alloc(NSLOT * 64 * 4);

    const int CT = 1 << ctLog;
    int NCperB = 0;
    for (int qt = 0; qt < 32; ++qt) NCperB += (qt + CT) >> ctLog;

    convw_kernel<<<256, 256, 0, stream>>>(Wq, bq, Wk, bk, Wv, bv, Wo, Wb, Wob, biasb);
    qkv_kernel<<<NM / 64, 512, 0, stream>>>(x, Wb, biasb, qb, kb, vtb);
    attn_kernel<<<8 * NCperB, 256, 0, stream>>>(qb, kb, vtb, Opart, lpart, ctLog, MAXC);
    combine_kernel<<<256, 256, 0, stream>>>(Opart, lpart, Wob, bo, out, ctLog, MAXC);
}

// Round 15
// 47.395 us; speedup vs baseline: 4.9852x; 1.0222x over previous
//
#include <hip/hip_runtime.h>
#include <hip/hip_bf16.h>

#define NB 8
#define NS 2048
#define ND 1024
#define NH 64
#define NM (NB*NS)   // 16384 rows

typedef __attribute__((ext_vector_type(8))) short short8;
typedef __attribute__((ext_vector_type(4))) short short4v;
typedef __attribute__((ext_vector_type(4))) float f32x4;
typedef __attribute__((ext_vector_type(4))) float f4;
typedef __attribute__((ext_vector_type(2))) unsigned int uint2v;

// q pre-scale: fold 1/sqrt(64) and log2(e) so attention uses exp2 directly.
#define QSCALE (0.125f * 1.44269504088896340736f)

__device__ __forceinline__ unsigned short f2bf(float f) {
    union { __hip_bfloat16 h; unsigned short u; } cv;
    cv.h = __float2bfloat16(f);   // HW RTNE convert
    return cv.u;
}

// Barrier WITHOUT the vmcnt(0) drain __syncthreads would emit.
__device__ __forceinline__ void barrier_nd() {
    asm volatile("s_waitcnt lgkmcnt(0)" ::: "memory");
    __builtin_amdgcn_s_barrier();
    asm volatile("" ::: "memory");
}

// ---------------------------------------------------------------------------
// Kernel 0: weights -> bf16. Rows 0..63 Wq (pre-scaled), 64..127 Wk,
// 128..191 Wv (row-major [row][k]); plus Wob (bf16 Wo) and biasb.
// ---------------------------------------------------------------------------
__global__ __launch_bounds__(256) void convw_kernel(
    const float* __restrict__ Wq, const float* __restrict__ bq,
    const float* __restrict__ Wk, const float* __restrict__ bk,
    const float* __restrict__ Wv, const float* __restrict__ bv,
    const float* __restrict__ Wo,
    unsigned short* __restrict__ Wb, unsigned short* __restrict__ Wob,
    float* __restrict__ biasb)
{
    const int row = blockIdx.x;   // 0..255
    const int t = threadIdx.x;    // 0..255
    if (row < 192) {
        const float* W = row < 64 ? Wq : (row < 128 ? Wk : Wv);
        const float sc = row < 64 ? QSCALE : 1.0f;
        f4 v = *(const f4*)&W[(size_t)(row & 63) * ND + t * 4];
        short4v o;
#pragma unroll
        for (int j = 0; j < 4; ++j) o[j] = (short)f2bf(v[j] * sc);
        *(short4v*)&Wb[(size_t)row * ND + t * 4] = o;
        if (row == 0 && t < 192) {
            const float* bsrc = t < 64 ? bq : (t < 128 ? bk : bv);
            biasb[t] = bsrc[t & 63] * (t < 64 ? QSCALE : 1.0f);
        }
    } else if (t < 16) {
        f4 v = *(const f4*)&Wo[(size_t)(row - 192) * 64 + t * 4];
        short4v o;
#pragma unroll
        for (int j = 0; j < 4; ++j) o[j] = (short)f2bf(v[j]);
        *(short4v*)&Wob[(size_t)(row - 192) * 64 + t * 4] = o;
    }
}

// ---------------------------------------------------------------------------
// Kernel 1: QKV projection (R14: 3-deep register prefetch, barrier_nd).
// ---------------------------------------------------------------------------
__global__ __launch_bounds__(512, 2) void qkv_kernel(
    const float* __restrict__ x, const unsigned short* __restrict__ Wb,
    const float* __restrict__ biasb,
    unsigned short* __restrict__ q, unsigned short* __restrict__ k,
    unsigned short* __restrict__ vT)
{
    __shared__ unsigned short As[2][64 * 64];
    __shared__ unsigned short Bs[2][192 * 64];

    const int t = threadIdx.x;
    const int lane = t & 63, g = lane >> 4, li = lane & 15;
    const int w = t >> 6, rg = w >> 2, cg = w & 3;
    const int m0 = blockIdx.x * 64;
    const int arow = t >> 3, ach = t & 7;

    f32x4 acc[2][3];
#pragma unroll
    for (int a = 0; a < 2; ++a)
#pragma unroll
        for (int nf = 0; nf < 3; ++nf) acc[a][nf] = (f32x4)0.f;

    f4 xa[3][2]; short8 wr[3][3];   // 3 slots: issue->consume = 2 iters

#define QKV_LOAD(KS, SL)                                                          \
    {                                                                             \
        const float* p_ = &x[(size_t)(m0 + arow) * ND + (KS) * 64 + ach * 8];     \
        xa[SL][0] = *(const f4*)p_; xa[SL][1] = *(const f4*)(p_ + 4);             \
        wr[SL][0] = *(const short8*)&Wb[(size_t)(t >> 3) * ND + (KS) * 64 + (t & 7) * 8];                  \
        wr[SL][1] = *(const short8*)&Wb[(size_t)((t + 512) >> 3) * ND + (KS) * 64 + ((t + 512) & 7) * 8];  \
        wr[SL][2] = *(const short8*)&Wb[(size_t)((t + 1024) >> 3) * ND + (KS) * 64 + ((t + 1024) & 7) * 8];\
    }

#define QKV_COMMIT(SL, BUF)                                                       \
    {                                                                             \
        short8 av_;                                                               \
        for (int j_ = 0; j_ < 4; ++j_) {                                          \
            av_[j_] = (short)f2bf(xa[SL][0][j_]);                                 \
            av_[j_ + 4] = (short)f2bf(xa[SL][1][j_]);                             \
        }                                                                         \
        *(short8*)&As[BUF][arow * 64 + ((ach ^ (arow & 7)) << 3)] = av_;          \
        int r0_ = t >> 3, c0_ = t & 7;                                            \
        *(short8*)&Bs[BUF][r0_ * 64 + ((c0_ ^ (r0_ & 7)) << 3)] = wr[SL][0];      \
        int r1_ = (t + 512) >> 3, c1_ = (t + 512) & 7;                            \
        *(short8*)&Bs[BUF][r1_ * 64 + ((c1_ ^ (r1_ & 7)) << 3)] = wr[SL][1];      \
        int r2_ = (t + 1024) >> 3, c2_ = (t + 1024) & 7;                          \
        *(short8*)&Bs[BUF][r2_ * 64 + ((c2_ ^ (r2_ & 7)) << 3)] = wr[SL][2];      \
    }

    QKV_LOAD(0, 0);
    QKV_LOAD(1, 1);
    QKV_LOAD(2, 2);
    QKV_COMMIT(0, 0);
    barrier_nd();

#pragma unroll
    for (int ks = 0; ks < 16; ++ks) {
        const int cur = ks & 1;
        if (ks < 13) QKV_LOAD(ks + 3, (ks + 3) % 3);
#pragma unroll
        for (int h = 0; h < 2; ++h) {
            short8 af0 = *(const short8*)&As[cur][(rg * 32 + 0 + li) * 64 + (((g + 4 * h) ^ (li & 7)) << 3)];
            short8 af1 = *(const short8*)&As[cur][(rg * 32 + 16 + li) * 64 + (((g + 4 * h) ^ (li & 7)) << 3)];
#pragma unroll
            for (int nf = 0; nf < 3; ++nf) {
                short8 bf = *(const short8*)&Bs[cur][(cg * 48 + nf * 16 + li) * 64 + (((g + 4 * h) ^ (li & 7)) << 3)];
                acc[0][nf] = __builtin_amdgcn_mfma_f32_16x16x32_bf16(af0, bf, acc[0][nf], 0, 0, 0);
                acc[1][nf] = __builtin_amdgcn_mfma_f32_16x16x32_bf16(af1, bf, acc[1][nf], 0, 0, 0);
            }
        }
        if (ks < 15) QKV_COMMIT((ks + 1) % 3, cur ^ 1);
        barrier_nd();
    }

    // epilogue: bias + store (q,k row-major; v transposed [b][h][s])
#pragma unroll
    for (int nf = 0; nf < 3; ++nf) {
        const int col = cg * 48 + nf * 16 + li;
        const float bias = biasb[col];
#pragma unroll
        for (int a = 0; a < 2; ++a) {
            const int row0 = m0 + rg * 32 + a * 16 + 4 * g;
            if (col < 64) {
#pragma unroll
                for (int i = 0; i < 4; ++i)
                    q[(size_t)(row0 + i) * NH + col] = f2bf(acc[a][nf][i] + bias);
            } else if (col < 128) {
#pragma unroll
                for (int i = 0; i < 4; ++i)
                    k[(size_t)(row0 + i) * NH + (col - 64)] = f2bf(acc[a][nf][i] + bias);
            } else {
                short4v pk;
#pragma unroll
                for (int i = 0; i < 4; ++i) pk[i] = (short)f2bf(acc[a][nf][i] + bias);
                const int bb = row0 >> 11, s = row0 & 2047;
                *(short4v*)&vT[(size_t)(bb * NH + (col - 128)) * NS + s] = pk;
            }
        }
    }
}

// ---------------------------------------------------------------------------
// Kernel 2: split-KV causal attention — SWAPPED QK^T (s = K^T·Q): each lane
// holds P for one q (lane&15) at kv = 16*c4 + 4*g + i. P packed to bf16 in
// registers and committed with 4x ds_write_b64 (was 32x ds_write_b16).
// PV operands swapped (O^T = V^T · P). pf/vf reads unchanged.
// ---------------------------------------------------------------------------
__global__ __launch_bounds__(256, 2) void attn_kernel(
    const unsigned short* __restrict__ q, const unsigned short* __restrict__ k,
    const unsigned short* __restrict__ vT,
    float* __restrict__ Opart, float* __restrict__ lpart,
    int ctLog, int MAXC)
{
    __shared__ unsigned short Ks[2][64 * 64];
    __shared__ unsigned short Vs[2][64 * 64];
    __shared__ unsigned short Ps[4][16 * 64];

    const int t = threadIdx.x;
    const int w = t >> 6, lane = t & 63, g = lane >> 4, li = lane & 15;
    const int b = blockIdx.x & 7;          // batch -> XCD pinning
    const int pid = blockIdx.x >> 3;
    const int CT = 1 << ctLog;

    int qt = 0, c = 0;
    {
        int acc = 0;
        for (int u = 31; u >= 0; --u) {    // largest-work-first
            int nch = (u + CT) >> ctLog;
            if (pid < acc + nch) { qt = u; c = pid - acc; break; }
            acc += nch;
        }
    }
    const int t0 = c * CT;
    const int rem = qt + 1 - t0;
    const int tcount = rem < CT ? rem : CT;

    const size_t qkbase = (size_t)b * NS * NH;
    const int qrow = qt * 64 + w * 16 + li;
    const short8 qa0 = *(const short8*)&q[qkbase + (size_t)qrow * NH + g * 8];
    const short8 qa1 = *(const short8*)&q[qkbase + (size_t)qrow * NH + 32 + g * 8];

    float l_i = 0.f;
    f32x4 oacc[4];
#pragma unroll
    for (int i = 0; i < 4; ++i) oacc[i] = (f32x4)0.f;

    const int srow = t >> 3, sch = t & 7;
    short8 kreg0, kreg1, vreg0, vreg1;

    {
        const int kv0 = t0 * 64;
        kreg0 = *(const short8*)&k[qkbase + (size_t)(kv0 + srow) * NH + sch * 8];
        kreg1 = *(const short8*)&k[qkbase + (size_t)(kv0 + srow + 32) * NH + sch * 8];
        vreg0 = *(const short8*)&vT[(size_t)(b * NH + srow) * NS + kv0 + sch * 8];
        vreg1 = *(const short8*)&vT[(size_t)(b * NH + srow + 32) * NS + kv0 + sch * 8];
        *(short8*)&Ks[0][srow * 64 + ((sch ^ (srow & 7)) << 3)] = kreg0;
        *(short8*)&Ks[0][(srow + 32) * 64 + ((sch ^ (srow & 7)) << 3)] = kreg1;
        *(short8*)&Vs[0][srow * 64 + ((sch ^ (srow & 7)) << 3)] = vreg0;
        *(short8*)&Vs[0][(srow + 32) * 64 + ((sch ^ (srow & 7)) << 3)] = vreg1;
    }
    barrier_nd();

    for (int tt = 0; tt < tcount; ++tt) {
        const int cur = tt & 1;
        const int kv0 = (t0 + tt) * 64;
        if (tt + 1 < tcount) {   // issue next-tile loads early (T14)
            const int nv0 = kv0 + 64;
            kreg0 = *(const short8*)&k[qkbase + (size_t)(nv0 + srow) * NH + sch * 8];
            kreg1 = *(const short8*)&k[qkbase + (size_t)(nv0 + srow + 32) * NH + sch * 8];
            vreg0 = *(const short8*)&vT[(size_t)(b * NH + srow) * NS + nv0 + sch * 8];
            vreg1 = *(const short8*)&vT[(size_t)(b * NH + srow + 32) * NS + nv0 + sch * 8];
        }
        // ---- QK^T swapped: s[c4] = K_c4^T Q -> D[kv-within-16][q] ----
        f32x4 s[4];
#pragma unroll
        for (int c4 = 0; c4 < 4; ++c4) {
            s[c4] = (f32x4)0.f;
            const int krow = 16 * c4 + li;
            short8 kf0 = *(const short8*)&Ks[cur][krow * 64 + ((g ^ (li & 7)) << 3)];
            s[c4] = __builtin_amdgcn_mfma_f32_16x16x32_bf16(kf0, qa0, s[c4], 0, 0, 0);
            short8 kf1 = *(const short8*)&Ks[cur][krow * 64 + (((g + 4) ^ (li & 7)) << 3)];
            s[c4] = __builtin_amdgcn_mfma_f32_16x16x32_bf16(kf1, qa1, s[c4], 0, 0, 0);
        }
        // ---- causal mask (diagonal tile): kv = 16c4+4g+i vs q = w*16+li ----
        if (kv0 == qt * 64) {
#pragma unroll
            for (int c4 = 0; c4 < 4; ++c4)
#pragma unroll
                for (int i = 0; i < 4; ++i)
                    if (16 * c4 + 4 * g + i > w * 16 + li) s[c4][i] = -1e30f;
        }
        // ---- no-max softmax in-place, scalar l accumulate ----
#pragma unroll
        for (int c4 = 0; c4 < 4; ++c4) {
#pragma unroll
            for (int i = 0; i < 4; ++i) {
                s[c4][i] = exp2f(fminf(s[c4][i], 80.f));
                l_i += s[c4][i];
            }
        }
        // ---- pack P to bf16 in regs, commit as 4x ds_write_b64 ----
#pragma unroll
        for (int c4 = 0; c4 < 4; ++c4) {
            unsigned lo = (unsigned)f2bf(s[c4][0]) | ((unsigned)f2bf(s[c4][1]) << 16);
            unsigned hi = (unsigned)f2bf(s[c4][2]) | ((unsigned)f2bf(s[c4][3]) << 16);
            uint2v pv; pv.x = lo; pv.y = hi;
            const int chunk = 2 * c4 + (g >> 1);
            *(uint2v*)&Ps[w][li * 64 + ((chunk ^ (li & 7)) << 3) + 4 * (g & 1)] = pv;
        }
        short8 pf0 = *(const short8*)&Ps[w][li * 64 + ((g ^ (li & 7)) << 3)];
        short8 pf1 = *(const short8*)&Ps[w][li * 64 + (((g + 4) ^ (li & 7)) << 3)];
        // ---- PV swapped: O^T = V^T P ----
#pragma unroll
        for (int nf = 0; nf < 4; ++nf) {
            const int vrow = nf * 16 + li;
            short8 vf0 = *(const short8*)&Vs[cur][vrow * 64 + ((g ^ (li & 7)) << 3)];
            short8 vf1 = *(const short8*)&Vs[cur][vrow * 64 + (((g + 4) ^ (li & 7)) << 3)];
            oacc[nf] = __builtin_amdgcn_mfma_f32_16x16x32_bf16(vf0, pf0, oacc[nf], 0, 0, 0);
            oacc[nf] = __builtin_amdgcn_mfma_f32_16x16x32_bf16(vf1, pf1, oacc[nf], 0, 0, 0);
        }
        if (tt + 1 < tcount) {   // commit next tile late
            *(short8*)&Ks[cur ^ 1][srow * 64 + ((sch ^ (srow & 7)) << 3)] = kreg0;
            *(short8*)&Ks[cur ^ 1][(srow + 32) * 64 + ((sch ^ (srow & 7)) << 3)] = kreg1;
            *(short8*)&Vs[cur ^ 1][srow * 64 + ((sch ^ (srow & 7)) << 3)] = vreg0;
            *(short8*)&Vs[cur ^ 1][(srow + 32) * 64 + ((sch ^ (srow & 7)) << 3)] = vreg1;
        }
        barrier_nd();
    }

    // ---- finish l: sum over the 4 lane-groups holding this q ----
    l_i += __shfl_xor(l_i, 16);
    l_i += __shfl_xor(l_i, 32);

    const size_t slot = (size_t)((b * 32 + qt) * MAXC + c);
    float* Op = Opart + slot * 4096;
    // D[r=feat-within-16][c=q]: row = 4g+i, col = li
#pragma unroll
    for (int nf = 0; nf < 4; ++nf)
#pragma unroll
        for (int i = 0; i < 4; ++i)
            Op[(w * 16 + li) * 64 + nf * 16 + 4 * g + i] = oacc[nf][i];
    if (g == 0)
        lpart[slot * 64 + w * 16 + li] = l_i;
}

// ---------------------------------------------------------------------------
// Kernel 3: combine partials + MFMA output projection (out = O @ Wo^T + bo)
// ---------------------------------------------------------------------------
__global__ __launch_bounds__(256, 2) void combine_kernel(
    const float* __restrict__ Opart, const float* __restrict__ lpart,
    const unsigned short* __restrict__ Wob, const float* __restrict__ bo,
    float* __restrict__ out, int ctLog, int MAXC)
{
    __shared__ unsigned short Osm[64 * 64];
    __shared__ float Linv[64];

    const int t = threadIdx.x;
    const int b = blockIdx.x & 7, qt = blockIdx.x >> 3;   // XCD-pinned to attn
    const int CT = 1 << ctLog;
    const int nch = (qt + CT) >> ctLog;
    const size_t base_slot = (size_t)(b * 32 + qt) * MAXC;

    if (t < 64) {
        float L = 0.f;
        for (int cc = 0; cc < nch; ++cc)
            L += lpart[(base_slot + cc) * 64 + t];
        Linv[t] = 1.f / L;
    }

    // accumulate O' across chunks: thread owns row r, 16 cols
    const int r = t >> 2, c0 = (t & 3) * 16;
    f4 a0 = (f4)0.f, a1 = (f4)0.f, a2 = (f4)0.f, a3 = (f4)0.f;
    for (int cc = 0; cc < nch; ++cc) {
        const float* P = Opart + (base_slot + cc) * 4096 + r * 64 + c0;
        a0 += *(const f4*)P; a1 += *(const f4*)(P + 4);
        a2 += *(const f4*)(P + 8); a3 += *(const f4*)(P + 12);
    }
    __syncthreads();
    {
        const float sc = Linv[r];
        short8 o0, o1;
#pragma unroll
        for (int j = 0; j < 4; ++j) {
            o0[j] = (short)f2bf(a0[j] * sc); o0[j + 4] = (short)f2bf(a1[j] * sc);
            o1[j] = (short)f2bf(a2[j] * sc); o1[j + 4] = (short)f2bf(a3[j] * sc);
        }
        const int ch0 = (t & 3) * 2;
        *(short8*)&Osm[r * 64 + ((ch0 ^ (r & 7)) << 3)] = o0;
        *(short8*)&Osm[r * 64 + (((ch0 + 1) ^ (r & 7)) << 3)] = o1;
    }
    __syncthreads();

    // oproj: 4 waves x 16 rows, MFMA, B = Wo rows (bf16, L2)
    const int w = t >> 6, lane = t & 63, g = lane >> 4, li = lane & 15;
    f32x4 acc[4];
#pragma unroll
    for (int nf = 0; nf < 4; ++nf) acc[nf] = (f32x4)0.f;
#pragma unroll
    for (int s = 0; s < 2; ++s) {
        const int rr = w * 16 + li;
        short8 af = *(const short8*)&Osm[rr * 64 + (((g + 4 * s) ^ (rr & 7)) << 3)];
#pragma unroll
        for (int nf = 0; nf < 4; ++nf) {
            short8 bf = *(const short8*)&Wob[(size_t)(nf * 16 + li) * 64 + s * 32 + g * 8];
            acc[nf] = __builtin_amdgcn_mfma_f32_16x16x32_bf16(af, bf, acc[nf], 0, 0, 0);
        }
    }
#pragma unroll
    for (int nf = 0; nf < 4; ++nf) {
        const float bias = bo[nf * 16 + li];
#pragma unroll
        for (int i = 0; i < 4; ++i) {
            const size_t row = (size_t)b * NS + qt * 64 + w * 16 + 4 * g + i;
            out[row * 64 + nf * 16 + li] = acc[nf][i] + bias;
        }
    }
}

// ---------------------------------------------------------------------------
extern "C" void kernel_launch(void* const* d_in, const int* in_sizes, int n_in,
                              void* d_out, int out_size, void* d_ws, size_t ws_size,
                              hipStream_t stream)
{
    const float* x  = (const float*)d_in[0];
    const float* Wq = (const float*)d_in[1];
    const float* bq = (const float*)d_in[2];
    const float* Wk = (const float*)d_in[3];
    const float* bk = (const float*)d_in[4];
    const float* Wv = (const float*)d_in[5];
    const float* bv = (const float*)d_in[6];
    const float* Wo = (const float*)d_in[7];
    const float* bo = (const float*)d_in[8];
    float* out = (float*)d_out;

    size_t off = 0;
    auto alloc = [&](size_t bytes) {
        char* p = (char*)d_ws + off;
        off += (bytes + 255) & ~(size_t)255;
        return (void*)p;
    };
    unsigned short* qb  = (unsigned short*)alloc((size_t)NM * NH * 2);
    unsigned short* kb  = (unsigned short*)alloc((size_t)NM * NH * 2);
    unsigned short* vtb = (unsigned short*)alloc((size_t)NM * NH * 2);
    unsigned short* Wb  = (unsigned short*)alloc((size_t)192 * ND * 2);
    unsigned short* Wob = (unsigned short*)alloc((size_t)64 * 64 * 2);
    float* biasb = (float*)alloc(192 * 4);
    const size_t base = off;

    // KV-chunk size: prefer CT=8 (640 blocks), fall back if ws is tight.
    int ctLog = 5, MAXC = 1;
    const int cands[3] = {3, 4, 5};
    for (int ci = 0; ci < 3; ++ci) {
        const int cl = cands[ci];
        const int mc = (31 >> cl) + 1;
        const size_t nslot = (size_t)256 * mc;
        const size_t need = base + nslot * (4096 + 64) * 4 + 8192;
        if (need <= ws_size) { ctLog = cl; MAXC = mc; break; }
    }
    const size_t NSLOT = (size_t)256 * MAXC;
    float* Opart = (float*)alloc(NSLOT * 4096 * 4);
    float* lpart = (float*)alloc(NSLOT * 64 * 4);

    const int CT = 1 << ctLog;
    int NCperB = 0;
    for (int qt = 0; qt < 32; ++qt) NCperB += (qt + CT) >> ctLog;

    convw_kernel<<<256, 256, 0, stream>>>(Wq, bq, Wk, bk, Wv, bv, Wo, Wb, Wob, biasb);
    qkv_kernel<<<NM / 64, 512, 0, stream>>>(x, Wb, biasb, qb, kb, vtb);
    attn_kernel<<<8 * NCperB, 256, 0, stream>>>(qb, kb, vtb, Opart, lpart, ctLog, MAXC);
    combine_kernel<<<256, 256, 0, stream>>>(Opart, lpart, Wob, bo, out, ctLog, MAXC);
}